// Round 1
// baseline (9588.728 us; speedup 1.0000x reference)
//
#include <hip/hip_runtime.h>
#include <math.h>

// ---------------- helpers ----------------

__device__ __forceinline__ unsigned fkey(float f) {
    unsigned u = __float_as_uint(f);
    return (u & 0x80000000u) ? ~u : (u | 0x80000000u);
}
__device__ __forceinline__ float fdecode(unsigned u) {
    unsigned b = (u & 0x80000000u) ? (u ^ 0x80000000u) : ~u;
    return __uint_as_float(b);
}

// ---------------- GEMM: P[n,512] = X[n,128] @ {Wq,Wk,Wv,Ws} + biases ----------------
// k' and v' columns also get +be (exact folding of the edge-embedding bias).
__global__ __launch_bounds__(256) void gemm_proj(
    const float* __restrict__ X, int M,
    const float* __restrict__ Wq, const float* __restrict__ bq,
    const float* __restrict__ Wk, const float* __restrict__ bk,
    const float* __restrict__ Wv, const float* __restrict__ bv,
    const float* __restrict__ Ws, const float* __restrict__ bs,
    const float* __restrict__ be,
    float* __restrict__ P)
{
    __shared__ float As[128][64];   // As[k][row]
    __shared__ float Bs[128][64];   // Bs[k][col]
    const int tid = threadIdx.x;
    const int row0 = blockIdx.x * 64;
    const int col0 = blockIdx.y * 64;          // global col in [0,512)
    const int sel = col0 >> 7;
    const int wc0 = col0 & 127;
    const float* W; const float* B;
    if (sel == 0)      { W = Wq; B = bq; }
    else if (sel == 1) { W = Wk; B = bk; }
    else if (sel == 2) { W = Wv; B = bv; }
    else               { W = Ws; B = bs; }
    const bool add_be = (sel == 1 || sel == 2);

#pragma unroll
    for (int u = 0; u < 8; ++u) {
        int flat = tid * 32 + u * 4;
        int r = flat >> 7, k = flat & 127;
        float4 v = make_float4(0.f, 0.f, 0.f, 0.f);
        if (row0 + r < M) v = *(const float4*)(X + (size_t)(row0 + r) * 128 + k);
        As[k + 0][r] = v.x; As[k + 1][r] = v.y; As[k + 2][r] = v.z; As[k + 3][r] = v.w;
    }
#pragma unroll
    for (int u = 0; u < 8; ++u) {
        int flat = tid * 32 + u * 4;
        int k = flat >> 6, c = flat & 63;
        *(float4*)(&Bs[k][c]) = *(const float4*)(W + k * 128 + wc0 + c);
    }
    __syncthreads();

    const int tx = tid & 15, ty = tid >> 4;
    const int r0 = ty * 4, c0 = tx * 4;
    float acc[4][4] = {};
#pragma unroll 8
    for (int k = 0; k < 128; ++k) {
        float4 a = *(const float4*)(&As[k][r0]);
        float4 b = *(const float4*)(&Bs[k][c0]);
        acc[0][0] += a.x * b.x; acc[0][1] += a.x * b.y; acc[0][2] += a.x * b.z; acc[0][3] += a.x * b.w;
        acc[1][0] += a.y * b.x; acc[1][1] += a.y * b.y; acc[1][2] += a.y * b.z; acc[1][3] += a.y * b.w;
        acc[2][0] += a.z * b.x; acc[2][1] += a.z * b.y; acc[2][2] += a.z * b.z; acc[2][3] += a.z * b.w;
        acc[3][0] += a.w * b.x; acc[3][1] += a.w * b.y; acc[3][2] += a.w * b.z; acc[3][3] += a.w * b.w;
    }
    float bias[4];
#pragma unroll
    for (int j = 0; j < 4; ++j) {
        int wc = wc0 + c0 + j;
        bias[j] = B[wc] + (add_be ? be[wc] : 0.f);
    }
#pragma unroll
    for (int i = 0; i < 4; ++i) {
        int gr = row0 + r0 + i;
        if (gr < M) {
            float4 o;
            o.x = acc[i][0] + bias[0];
            o.y = acc[i][1] + bias[1];
            o.z = acc[i][2] + bias[2];
            o.w = acc[i][3] + bias[3];
            *(float4*)(P + (size_t)gr * 512 + col0 + c0) = o;
        }
    }
}

// ---------------- qWe precompute ----------------
// layer1: qWe[n, h, k] = sum_c q[n,h,c] * We1[k, h*16+c]   (g = n*128 + h*16 + k)
__global__ __launch_bounds__(256) void qwe1_kernel(
    const float* __restrict__ P, const float* __restrict__ We1,
    float* __restrict__ qWe, int N)
{
    int g = blockIdx.x * blockDim.x + threadIdx.x;
    if (g >= N * 128) return;
    int n = g >> 7, rem = g & 127, h = rem >> 4, k = rem & 15;
    const float* q = P + (size_t)n * 512 + h * 16;
    const float* w = We1 + k * 128 + h * 16;
    float s = 0.f;
#pragma unroll
    for (int c = 0; c < 16; ++c) s += q[c] * w[c];
    qWe[g] = s;
}

// layer2: qWe[n, k] = sum_c q[n,c] * We2[k, c]
__global__ __launch_bounds__(256) void qwe2_kernel(
    const float* __restrict__ P, const float* __restrict__ We2,
    float* __restrict__ qWe, int N)
{
    int g = blockIdx.x * blockDim.x + threadIdx.x;
    if (g >= N * 16) return;
    int n = g >> 4, k = g & 15;
    const float4* q = (const float4*)(P + (size_t)n * 512);
    const float4* w = (const float4*)(We2 + (size_t)k * 128);
    float s = 0.f;
#pragma unroll
    for (int i = 0; i < 32; ++i) {
        float4 a = q[i], b = w[i];
        s += a.x * b.x + a.y * b.y + a.z * b.z + a.w * b.w;
    }
    qWe[g] = s;
}

// ---------------- layer-1 edge passes (H=8, C=16) ----------------
__global__ __launch_bounds__(256) void score1_kernel(
    const float* __restrict__ P, const float* __restrict__ qWe,
    const float* __restrict__ ea, const int* __restrict__ ei,
    float* __restrict__ score, unsigned* __restrict__ m_u, int E)
{
    int g = blockIdx.x * blockDim.x + threadIdx.x;
    if (g >= E * 8) return;
    int e = g >> 3, h = g & 7;
    int src = ei[e], dst = ei[E + e];
    const float4* q  = (const float4*)(P + (size_t)dst * 512 + h * 16);
    const float4* kb = (const float4*)(P + (size_t)src * 512 + 128 + h * 16);
    const float4* qw = (const float4*)(qWe + (size_t)dst * 128 + h * 16);
    const float4* ev = (const float4*)(ea + (size_t)e * 16);
    float s = 0.f;
#pragma unroll
    for (int i = 0; i < 4; ++i) {
        float4 a = q[i], b = kb[i];
        s += a.x * b.x + a.y * b.y + a.z * b.z + a.w * b.w;
        float4 c = ev[i], d = qw[i];
        s += c.x * d.x + c.y * d.y + c.z * d.z + c.w * d.w;
    }
    s *= 0.25f;  // 1/sqrt(16)
    score[g] = s;
    atomicMax(m_u + (size_t)dst * 8 + h, fkey(s));
}

__global__ __launch_bounds__(256) void expsum1_kernel(
    const int* __restrict__ ei, const unsigned* __restrict__ m_u,
    float* __restrict__ score, float* __restrict__ den, int E)
{
    int g = blockIdx.x * blockDim.x + threadIdx.x;
    if (g >= E * 8) return;
    int e = g >> 3, h = g & 7;
    int dst = ei[E + e];
    float m = fdecode(m_u[(size_t)dst * 8 + h]);
    float ex = __expf(score[g] - m);
    score[g] = ex;
    unsafeAtomicAdd(den + (size_t)dst * 8 + h, ex);
}

__global__ __launch_bounds__(256) void agg1_kernel(
    const float* __restrict__ P, const float* __restrict__ ea,
    const float* __restrict__ We1, const int* __restrict__ ei,
    const float* __restrict__ score, const float* __restrict__ den,
    float* __restrict__ V, int E)
{
    int g = blockIdx.x * blockDim.x + threadIdx.x;
    if (g >= E * 8) return;
    int e = g >> 3, h = g & 7;
    int src = ei[e], dst = ei[E + e];
    float alpha = score[g] / (den[(size_t)dst * 8 + h] + 1e-16f);
    const float* eav = ea + (size_t)e * 16;
    float eh[16] = {};
#pragma unroll
    for (int k = 0; k < 16; ++k) {
        float a = eav[k];
        const float* w = We1 + k * 128 + h * 16;
#pragma unroll
        for (int c = 0; c < 16; ++c) eh[c] += a * w[c];
    }
    const float* vp = P + (size_t)src * 512 + 256 + h * 16;  // v' = x@Wv+bv+be
    float* Vd = V + (size_t)dst * 128 + h * 16;
#pragma unroll
    for (int c = 0; c < 16; ++c)
        unsafeAtomicAdd(Vd + c, alpha * (vp[c] + eh[c]));
}

__global__ __launch_bounds__(256) void fin1_kernel(
    const float* __restrict__ V, const float* __restrict__ P,
    float* __restrict__ h1, int N)
{
    int g = blockIdx.x * blockDim.x + threadIdx.x;
    if (g >= N * 128) return;
    int n = g >> 7, c = g & 127;
    float v = V[g] + P[(size_t)n * 512 + 384 + c];  // + skip (x@Ws+bs)
    h1[g] = (v > 0.f) ? v : 0.01f * v;              // leaky relu
}

// ---------------- layer-2 edge passes (H=1, C=128) ----------------
__global__ __launch_bounds__(256) void score2_kernel(
    const float* __restrict__ P, const float* __restrict__ qWe,
    const float* __restrict__ ea, const int* __restrict__ ei,
    float* __restrict__ score, unsigned* __restrict__ m_u, int E)
{
    int e = blockIdx.x * blockDim.x + threadIdx.x;
    if (e >= E) return;
    int src = ei[e], dst = ei[E + e];
    const float4* q  = (const float4*)(P + (size_t)dst * 512);
    const float4* kb = (const float4*)(P + (size_t)src * 512 + 128);
    float s = 0.f;
#pragma unroll
    for (int i = 0; i < 32; ++i) {
        float4 a = q[i], b = kb[i];
        s += a.x * b.x + a.y * b.y + a.z * b.z + a.w * b.w;
    }
    const float* eav = ea + (size_t)e * 16;
    const float* qw = qWe + (size_t)dst * 16;
#pragma unroll
    for (int k = 0; k < 16; ++k) s += eav[k] * qw[k];
    s *= 0.08838834764831845f;  // 1/sqrt(128)
    score[e] = s;
    atomicMax(m_u + dst, fkey(s));
}

__global__ __launch_bounds__(256) void expsum2_kernel(
    const int* __restrict__ ei, const unsigned* __restrict__ m_u,
    float* __restrict__ score, float* __restrict__ den, int E)
{
    int e = blockIdx.x * blockDim.x + threadIdx.x;
    if (e >= E) return;
    int dst = ei[E + e];
    float m = fdecode(m_u[dst]);
    float ex = __expf(score[e] - m);
    score[e] = ex;
    unsafeAtomicAdd(den + dst, ex);
}

__global__ __launch_bounds__(256) void agg2_kernel(
    const float* __restrict__ P, const float* __restrict__ ea,
    const int* __restrict__ ei, const float* __restrict__ score,
    const float* __restrict__ den, float* __restrict__ V,
    float* __restrict__ A, int E)
{
    int e = blockIdx.x * blockDim.x + threadIdx.x;
    if (e >= E) return;
    int src = ei[e], dst = ei[E + e];
    float alpha = score[e] / (den[dst] + 1e-16f);
    const float* eav = ea + (size_t)e * 16;
    float* Ad = A + (size_t)dst * 16;
#pragma unroll
    for (int k = 0; k < 16; ++k) unsafeAtomicAdd(Ad + k, alpha * eav[k]);
    const float4* vp = (const float4*)(P + (size_t)src * 512 + 256);  // v' = h1@Wv2+bv2+be2
    float* Vd = V + (size_t)dst * 128;
#pragma unroll
    for (int i = 0; i < 32; ++i) {
        float4 v = vp[i];
        unsafeAtomicAdd(Vd + i * 4 + 0, alpha * v.x);
        unsafeAtomicAdd(Vd + i * 4 + 1, alpha * v.y);
        unsafeAtomicAdd(Vd + i * 4 + 2, alpha * v.z);
        unsafeAtomicAdd(Vd + i * 4 + 3, alpha * v.w);
    }
}

__global__ __launch_bounds__(256) void fin2_kernel(
    const float* __restrict__ V, const float* __restrict__ A,
    const float* __restrict__ We2, const float* __restrict__ P,
    float* __restrict__ out, int N)
{
    int g = blockIdx.x * blockDim.x + threadIdx.x;
    if (g >= N * 128) return;
    int n = g >> 7, c = g & 127;
    float s = V[g] + P[(size_t)n * 512 + 384 + c];  // + skip (h1@Ws2+bs2)
    const float* a = A + (size_t)n * 16;
#pragma unroll
    for (int k = 0; k < 16; ++k) s += a[k] * We2[k * 128 + c];  // + (sum alpha*ea)@We2
    out[g] = s;
}

// ---------------- launch ----------------
extern "C" void kernel_launch(void* const* d_in, const int* in_sizes, int n_in,
                              void* d_out, int out_size, void* d_ws, size_t ws_size,
                              hipStream_t stream)
{
    const float* x  = (const float*)d_in[0];
    const int*   ei = (const int*)d_in[1];
    const float* ea = (const float*)d_in[2];
    const float *Wq1 = (const float*)d_in[3],  *bq1 = (const float*)d_in[4];
    const float *Wk1 = (const float*)d_in[5],  *bk1 = (const float*)d_in[6];
    const float *Wv1 = (const float*)d_in[7],  *bv1 = (const float*)d_in[8];
    const float *We1 = (const float*)d_in[9],  *be1 = (const float*)d_in[10];
    const float *Ws1 = (const float*)d_in[11], *bs1 = (const float*)d_in[12];
    const float *Wq2 = (const float*)d_in[13], *bq2 = (const float*)d_in[14];
    const float *Wk2 = (const float*)d_in[15], *bk2 = (const float*)d_in[16];
    const float *Wv2 = (const float*)d_in[17], *bv2 = (const float*)d_in[18];
    const float *We2 = (const float*)d_in[19], *be2 = (const float*)d_in[20];
    const float *Ws2 = (const float*)d_in[21], *bs2 = (const float*)d_in[22];

    const int N = in_sizes[0] / 128;
    const int E = in_sizes[1] / 2;

    char* ws = (char*)d_ws;
    size_t off = 0;
    auto alloc = [&](size_t bytes) -> void* {
        void* p = ws + off;
        off = (off + bytes + 255) & ~(size_t)255;
        return p;
    };
    float*    P     = (float*)alloc((size_t)N * 512 * 4);  // q | k'+be | v'+be | s
    float*    qWe   = (float*)alloc((size_t)N * 128 * 4);
    float*    h1    = (float*)alloc((size_t)N * 128 * 4);
    float*    score = (float*)alloc((size_t)E * 8 * 4);
    unsigned* m_u   = (unsigned*)alloc((size_t)N * 8 * 4);
    float*    den   = (float*)alloc((size_t)N * 8 * 4);
    float*    V     = (float*)alloc((size_t)N * 128 * 4);
    float*    A     = (float*)alloc((size_t)N * 16 * 4);

    dim3 gemm_grid((N + 63) / 64, 8);
    const int tn  = N * 128;
    const int te1 = E * 8;

    // ---- layer 1 (H=8, C=16, concat) ----
    gemm_proj<<<gemm_grid, 256, 0, stream>>>(x, N, Wq1, bq1, Wk1, bk1, Wv1, bv1, Ws1, bs1, be1, P);
    qwe1_kernel<<<(tn + 255) / 256, 256, 0, stream>>>(P, We1, qWe, N);
    hipMemsetAsync(m_u, 0, (size_t)N * 8 * 4, stream);
    hipMemsetAsync(den, 0, (size_t)N * 8 * 4, stream);
    hipMemsetAsync(V,   0, (size_t)N * 128 * 4, stream);
    score1_kernel<<<(te1 + 255) / 256, 256, 0, stream>>>(P, qWe, ea, ei, score, m_u, E);
    expsum1_kernel<<<(te1 + 255) / 256, 256, 0, stream>>>(ei, m_u, score, den, E);
    agg1_kernel<<<(te1 + 255) / 256, 256, 0, stream>>>(P, ea, We1, ei, score, den, V, E);
    fin1_kernel<<<(tn + 255) / 256, 256, 0, stream>>>(V, P, h1, N);

    // ---- layer 2 (H=1, C=128, mean==identity) ----
    gemm_proj<<<gemm_grid, 256, 0, stream>>>(h1, N, Wq2, bq2, Wk2, bk2, Wv2, bv2, Ws2, bs2, be2, P);
    qwe2_kernel<<<(N * 16 + 255) / 256, 256, 0, stream>>>(P, We2, qWe, N);
    hipMemsetAsync(m_u, 0, (size_t)N * 4, stream);
    hipMemsetAsync(den, 0, (size_t)N * 4, stream);
    hipMemsetAsync(V,   0, (size_t)N * 128 * 4, stream);
    hipMemsetAsync(A,   0, (size_t)N * 16 * 4, stream);
    score2_kernel<<<(E + 255) / 256, 256, 0, stream>>>(P, qWe, ea, ei, score, m_u, E);
    expsum2_kernel<<<(E + 255) / 256, 256, 0, stream>>>(ei, m_u, score, den, E);
    agg2_kernel<<<(E + 255) / 256, 256, 0, stream>>>(P, ea, ei, score, den, V, A, E);
    fin2_kernel<<<(tn + 255) / 256, 256, 0, stream>>>(V, A, We2, P, (float*)d_out, N);
}

// Round 2
// 1279.737 us; speedup vs baseline: 7.4927x; 7.4927x over previous
//
#include <hip/hip_runtime.h>
#include <math.h>

// ================= GEMM: P[n,512] = X[n,128] @ {Wq,Wk,Wv,Ws} + biases =================
// k' and v' columns also get +be (exact folding of the edge-embedding bias).
__global__ __launch_bounds__(256) void gemm_proj(
    const float* __restrict__ X, int M,
    const float* __restrict__ Wq, const float* __restrict__ bq,
    const float* __restrict__ Wk, const float* __restrict__ bk,
    const float* __restrict__ Wv, const float* __restrict__ bv,
    const float* __restrict__ Ws, const float* __restrict__ bs,
    const float* __restrict__ be,
    float* __restrict__ P)
{
    __shared__ float As[128][64];   // As[k][row]
    __shared__ float Bs[128][64];   // Bs[k][col]
    const int tid = threadIdx.x;
    const int row0 = blockIdx.x * 64;
    const int col0 = blockIdx.y * 64;          // global col in [0,512)
    const int sel = col0 >> 7;
    const int wc0 = col0 & 127;
    const float* W; const float* B;
    if (sel == 0)      { W = Wq; B = bq; }
    else if (sel == 1) { W = Wk; B = bk; }
    else if (sel == 2) { W = Wv; B = bv; }
    else               { W = Ws; B = bs; }
    const bool add_be = (sel == 1 || sel == 2);

#pragma unroll
    for (int u = 0; u < 8; ++u) {
        int flat = tid * 32 + u * 4;
        int r = flat >> 7, k = flat & 127;
        float4 v = make_float4(0.f, 0.f, 0.f, 0.f);
        if (row0 + r < M) v = *(const float4*)(X + (size_t)(row0 + r) * 128 + k);
        As[k + 0][r] = v.x; As[k + 1][r] = v.y; As[k + 2][r] = v.z; As[k + 3][r] = v.w;
    }
#pragma unroll
    for (int u = 0; u < 8; ++u) {
        int flat = tid * 32 + u * 4;
        int k = flat >> 6, c = flat & 63;
        *(float4*)(&Bs[k][c]) = *(const float4*)(W + k * 128 + wc0 + c);
    }
    __syncthreads();

    const int tx = tid & 15, ty = tid >> 4;
    const int r0 = ty * 4, c0 = tx * 4;
    float acc[4][4] = {};
#pragma unroll 8
    for (int k = 0; k < 128; ++k) {
        float4 a = *(const float4*)(&As[k][r0]);
        float4 b = *(const float4*)(&Bs[k][c0]);
        acc[0][0] += a.x * b.x; acc[0][1] += a.x * b.y; acc[0][2] += a.x * b.z; acc[0][3] += a.x * b.w;
        acc[1][0] += a.y * b.x; acc[1][1] += a.y * b.y; acc[1][2] += a.y * b.z; acc[1][3] += a.y * b.w;
        acc[2][0] += a.z * b.x; acc[2][1] += a.z * b.y; acc[2][2] += a.z * b.z; acc[2][3] += a.z * b.w;
        acc[3][0] += a.w * b.x; acc[3][1] += a.w * b.y; acc[3][2] += a.w * b.z; acc[3][3] += a.w * b.w;
    }
    float bias[4];
#pragma unroll
    for (int j = 0; j < 4; ++j) {
        int wc = wc0 + c0 + j;
        bias[j] = B[wc] + (add_be ? be[wc] : 0.f);
    }
#pragma unroll
    for (int i = 0; i < 4; ++i) {
        int gr = row0 + r0 + i;
        if (gr < M) {
            float4 o;
            o.x = acc[i][0] + bias[0];
            o.y = acc[i][1] + bias[1];
            o.z = acc[i][2] + bias[2];
            o.w = acc[i][3] + bias[3];
            *(float4*)(P + (size_t)gr * 512 + col0 + c0) = o;
        }
    }
}

// ================= CSR build (int atomics only) =================
__global__ __launch_bounds__(256) void degree_kernel(
    const int* __restrict__ ei, int* __restrict__ deg, int E)
{
    int e = blockIdx.x * blockDim.x + threadIdx.x;
    if (e < E) atomicAdd(&deg[ei[E + e]], 1);
}

// single-block Hillis-Steele scan over N elements; writes rowptr (exclusive+1) and cursor (exclusive)
__global__ __launch_bounds__(1024) void scan_kernel(
    const int* __restrict__ deg, int* __restrict__ rowptr,
    int* __restrict__ cursor, int N)
{
    __shared__ int tmp[1024];
    __shared__ int carry_s;
    if (threadIdx.x == 0) { carry_s = 0; rowptr[0] = 0; }
    __syncthreads();
    for (int base = 0; base < N; base += 1024) {
        int i = base + threadIdx.x;
        int v = (i < N) ? deg[i] : 0;
        tmp[threadIdx.x] = v;
        __syncthreads();
        for (int ofs = 1; ofs < 1024; ofs <<= 1) {
            int t = (threadIdx.x >= ofs) ? tmp[threadIdx.x - ofs] : 0;
            __syncthreads();
            tmp[threadIdx.x] += t;
            __syncthreads();
        }
        int carry = carry_s;
        if (i < N) {
            rowptr[i + 1] = carry + tmp[threadIdx.x];
            cursor[i]     = carry + tmp[threadIdx.x] - v;
        }
        __syncthreads();
        if (threadIdx.x == 1023) carry_s = carry + tmp[1023];
        __syncthreads();
    }
}

__global__ __launch_bounds__(256) void scatter_kernel(
    const int* __restrict__ ei, int* __restrict__ cursor,
    int* __restrict__ perm, int E)
{
    int e = blockIdx.x * blockDim.x + threadIdx.x;
    if (e < E) {
        int pos = atomicAdd(&cursor[ei[E + e]], 1);
        perm[pos] = e;
    }
}

// ================= qWe precompute =================
// layer1: qWe[n, h, k] = sum_c q[n,h,c] * We1[k, h*16+c]
__global__ __launch_bounds__(256) void qwe1_kernel(
    const float* __restrict__ P, const float* __restrict__ We1,
    float* __restrict__ qWe, int N)
{
    int g = blockIdx.x * blockDim.x + threadIdx.x;
    if (g >= N * 128) return;
    int n = g >> 7, rem = g & 127, h = rem >> 4, k = rem & 15;
    const float* q = P + (size_t)n * 512 + h * 16;
    const float* w = We1 + k * 128 + h * 16;
    float s = 0.f;
#pragma unroll
    for (int c = 0; c < 16; ++c) s += q[c] * w[c];
    qWe[g] = s;
}

// layer2: qWe[n, k] = sum_c q[n,c] * We2[k, c]
__global__ __launch_bounds__(256) void qwe2_kernel(
    const float* __restrict__ P, const float* __restrict__ We2,
    float* __restrict__ qWe, int N)
{
    int g = blockIdx.x * blockDim.x + threadIdx.x;
    if (g >= N * 16) return;
    int n = g >> 4, k = g & 15;
    const float4* q = (const float4*)(P + (size_t)n * 512);
    const float4* w = (const float4*)(We2 + (size_t)k * 128);
    float s = 0.f;
#pragma unroll
    for (int i = 0; i < 32; ++i) {
        float4 a = q[i], b = w[i];
        s += a.x * b.x + a.y * b.y + a.z * b.z + a.w * b.w;
    }
    qWe[g] = s;
}

// ================= edge-parallel scores (no atomics) =================
__global__ __launch_bounds__(256) void score1_kernel(
    const float* __restrict__ P, const float* __restrict__ qWe,
    const float* __restrict__ ea, const int* __restrict__ ei,
    float* __restrict__ score, int E)
{
    int g = blockIdx.x * blockDim.x + threadIdx.x;
    if (g >= E * 8) return;
    int e = g >> 3, h = g & 7;
    int src = ei[e], dst = ei[E + e];
    const float4* q  = (const float4*)(P + (size_t)dst * 512 + h * 16);
    const float4* kb = (const float4*)(P + (size_t)src * 512 + 128 + h * 16);
    const float4* qw = (const float4*)(qWe + (size_t)dst * 128 + h * 16);
    const float4* ev = (const float4*)(ea + (size_t)e * 16);
    float s = 0.f;
#pragma unroll
    for (int i = 0; i < 4; ++i) {
        float4 a = q[i], b = kb[i];
        s += a.x * b.x + a.y * b.y + a.z * b.z + a.w * b.w;
        float4 c = ev[i], d = qw[i];
        s += c.x * d.x + c.y * d.y + c.z * d.z + c.w * d.w;
    }
    score[g] = s * 0.25f;  // 1/sqrt(16)
}

__global__ __launch_bounds__(256) void score2_kernel(
    const float* __restrict__ P, const float* __restrict__ qWe,
    const float* __restrict__ ea, const int* __restrict__ ei,
    float* __restrict__ score, int E)
{
    int e = blockIdx.x * blockDim.x + threadIdx.x;
    if (e >= E) return;
    int src = ei[e], dst = ei[E + e];
    const float4* q  = (const float4*)(P + (size_t)dst * 512);
    const float4* kb = (const float4*)(P + (size_t)src * 512 + 128);
    float s = 0.f;
#pragma unroll
    for (int i = 0; i < 32; ++i) {
        float4 a = q[i], b = kb[i];
        s += a.x * b.x + a.y * b.y + a.z * b.z + a.w * b.w;
    }
    const float* eav = ea + (size_t)e * 16;
    const float* qw = qWe + (size_t)dst * 16;
#pragma unroll
    for (int k = 0; k < 16; ++k) s += eav[k] * qw[k];
    score[e] = s * 0.08838834764831845f;  // 1/sqrt(128)
}

// ================= per-node gather aggregation (no atomics) =================
// One wave per node; lane handles 2 channels. Layer 1: 8 heads, per-head
// softmax reduced over aligned 8-lane groups (lane>>3 == head of this lane's
// channels). Fuses expsum + aggregation + skip + leaky-relu.
__global__ __launch_bounds__(256) void agg1_node(
    const float* __restrict__ P, const float* __restrict__ score,
    const float* __restrict__ ea, const float* __restrict__ We1,
    const int* __restrict__ ei, const int* __restrict__ rowptr,
    const int* __restrict__ perm, float* __restrict__ h1, int N)
{
    int lane = threadIdx.x & 63;
    int node = blockIdx.x * 4 + (threadIdx.x >> 6);
    if (node >= N) return;
    int beg = rowptr[node], deg = rowptr[node + 1] - beg;
    int h = lane >> 3, sub = lane & 7;

    float m = -INFINITY;
    for (int i = sub; i < deg; i += 8)
        m = fmaxf(m, score[(size_t)perm[beg + i] * 8 + h]);
#pragma unroll
    for (int mk = 1; mk < 8; mk <<= 1) m = fmaxf(m, __shfl_xor(m, mk, 64));

    float den = 0.f;
    for (int i = sub; i < deg; i += 8)
        den += __expf(score[(size_t)perm[beg + i] * 8 + h] - m);
#pragma unroll
    for (int mk = 1; mk < 8; mk <<= 1) den += __shfl_xor(den, mk, 64);
    den += 1e-16f;

    const int c0 = lane * 2;
    float w0[16], w1[16];
#pragma unroll
    for (int k = 0; k < 16; ++k) { w0[k] = We1[k * 128 + c0]; w1[k] = We1[k * 128 + c0 + 1]; }

    float acc0 = 0.f, acc1 = 0.f;
    for (int i = 0; i < deg; ++i) {
        int e = perm[beg + i];
        float alpha = __expf(score[(size_t)e * 8 + h] - m) / den;
        int src = ei[e];
        float2 v = *(const float2*)(P + (size_t)src * 512 + 256 + c0);
        const float* eav = ea + (size_t)e * 16;
        float e0 = 0.f, e1 = 0.f;
#pragma unroll
        for (int k = 0; k < 16; ++k) { float a = eav[k]; e0 += a * w0[k]; e1 += a * w1[k]; }
        acc0 += alpha * (v.x + e0);
        acc1 += alpha * (v.y + e1);
    }
    float s0 = acc0 + P[(size_t)node * 512 + 384 + c0];
    float s1 = acc1 + P[(size_t)node * 512 + 384 + c0 + 1];
    h1[(size_t)node * 128 + c0]     = (s0 > 0.f) ? s0 : 0.01f * s0;
    h1[(size_t)node * 128 + c0 + 1] = (s1 > 0.f) ? s1 : 0.01f * s1;
}

// Layer 2: single head, full-wave softmax reduction. Fuses skip add.
__global__ __launch_bounds__(256) void agg2_node(
    const float* __restrict__ P, const float* __restrict__ score,
    const float* __restrict__ ea, const float* __restrict__ We2,
    const int* __restrict__ ei, const int* __restrict__ rowptr,
    const int* __restrict__ perm, float* __restrict__ out, int N)
{
    int lane = threadIdx.x & 63;
    int node = blockIdx.x * 4 + (threadIdx.x >> 6);
    if (node >= N) return;
    int beg = rowptr[node], deg = rowptr[node + 1] - beg;

    float m = -INFINITY;
    for (int i = lane; i < deg; i += 64) m = fmaxf(m, score[perm[beg + i]]);
#pragma unroll
    for (int mk = 1; mk < 64; mk <<= 1) m = fmaxf(m, __shfl_xor(m, mk, 64));

    float den = 0.f;
    for (int i = lane; i < deg; i += 64) den += __expf(score[perm[beg + i]] - m);
#pragma unroll
    for (int mk = 1; mk < 64; mk <<= 1) den += __shfl_xor(den, mk, 64);
    den += 1e-16f;

    const int c0 = lane * 2;
    float w0[16], w1[16];
#pragma unroll
    for (int k = 0; k < 16; ++k) { w0[k] = We2[k * 128 + c0]; w1[k] = We2[k * 128 + c0 + 1]; }

    float acc0 = 0.f, acc1 = 0.f;
    for (int i = 0; i < deg; ++i) {
        int e = perm[beg + i];
        float alpha = __expf(score[e] - m) / den;
        int src = ei[e];
        float2 v = *(const float2*)(P + (size_t)src * 512 + 256 + c0);
        const float* eav = ea + (size_t)e * 16;
        float e0 = 0.f, e1 = 0.f;
#pragma unroll
        for (int k = 0; k < 16; ++k) { float a = eav[k]; e0 += a * w0[k]; e1 += a * w1[k]; }
        acc0 += alpha * (v.x + e0);
        acc1 += alpha * (v.y + e1);
    }
    out[(size_t)node * 128 + c0]     = acc0 + P[(size_t)node * 512 + 384 + c0];
    out[(size_t)node * 128 + c0 + 1] = acc1 + P[(size_t)node * 512 + 384 + c0 + 1];
}

// ================= launch =================
extern "C" void kernel_launch(void* const* d_in, const int* in_sizes, int n_in,
                              void* d_out, int out_size, void* d_ws, size_t ws_size,
                              hipStream_t stream)
{
    const float* x  = (const float*)d_in[0];
    const int*   ei = (const int*)d_in[1];
    const float* ea = (const float*)d_in[2];
    const float *Wq1 = (const float*)d_in[3],  *bq1 = (const float*)d_in[4];
    const float *Wk1 = (const float*)d_in[5],  *bk1 = (const float*)d_in[6];
    const float *Wv1 = (const float*)d_in[7],  *bv1 = (const float*)d_in[8];
    const float *We1 = (const float*)d_in[9],  *be1 = (const float*)d_in[10];
    const float *Ws1 = (const float*)d_in[11], *bs1 = (const float*)d_in[12];
    const float *Wq2 = (const float*)d_in[13], *bq2 = (const float*)d_in[14];
    const float *Wk2 = (const float*)d_in[15], *bk2 = (const float*)d_in[16];
    const float *Wv2 = (const float*)d_in[17], *bv2 = (const float*)d_in[18];
    const float *We2 = (const float*)d_in[19], *be2 = (const float*)d_in[20];
    const float *Ws2 = (const float*)d_in[21], *bs2 = (const float*)d_in[22];

    const int N = in_sizes[0] / 128;
    const int E = in_sizes[1] / 2;

    char* ws = (char*)d_ws;
    size_t off = 0;
    auto alloc = [&](size_t bytes) -> void* {
        void* p = ws + off;
        off = (off + bytes + 255) & ~(size_t)255;
        return p;
    };
    float* P      = (float*)alloc((size_t)N * 512 * 4);  // q | k'+be | v'+be | s
    float* qWe    = (float*)alloc((size_t)N * 128 * 4);
    float* h1     = (float*)alloc((size_t)N * 128 * 4);
    float* score  = (float*)alloc((size_t)E * 8 * 4);
    int*   deg    = (int*)alloc((size_t)N * 4);
    int*   rowptr = (int*)alloc((size_t)(N + 1) * 4);
    int*   cursor = (int*)alloc((size_t)N * 4);
    int*   perm   = (int*)alloc((size_t)E * 4);

    dim3 gemm_grid((N + 63) / 64, 8);
    const int tn  = N * 128;
    const int te1 = E * 8;
    const int node_blocks = (N + 3) / 4;

    // ---- CSR build (shared by both layers) ----
    hipMemsetAsync(deg, 0, (size_t)N * 4, stream);
    degree_kernel<<<(E + 255) / 256, 256, 0, stream>>>(ei, deg, E);
    scan_kernel<<<1, 1024, 0, stream>>>(deg, rowptr, cursor, N);
    scatter_kernel<<<(E + 255) / 256, 256, 0, stream>>>(ei, cursor, perm, E);

    // ---- layer 1 (H=8, C=16, concat) ----
    gemm_proj<<<gemm_grid, 256, 0, stream>>>(x, N, Wq1, bq1, Wk1, bk1, Wv1, bv1, Ws1, bs1, be1, P);
    qwe1_kernel<<<(tn + 255) / 256, 256, 0, stream>>>(P, We1, qWe, N);
    score1_kernel<<<(te1 + 255) / 256, 256, 0, stream>>>(P, qWe, ea, ei, score, E);
    agg1_node<<<node_blocks, 256, 0, stream>>>(P, score, ea, We1, ei, rowptr, perm, h1, N);

    // ---- layer 2 (H=1, C=128, mean==identity) ----
    gemm_proj<<<gemm_grid, 256, 0, stream>>>(h1, N, Wq2, bq2, Wk2, bk2, Wv2, bv2, Ws2, bs2, be2, P);
    qwe2_kernel<<<(N * 16 + 255) / 256, 256, 0, stream>>>(P, We2, qWe, N);
    score2_kernel<<<(E + 255) / 256, 256, 0, stream>>>(P, qWe, ea, ei, score, E);
    agg2_node<<<node_blocks, 256, 0, stream>>>(P, score, ea, We2, ei, rowptr, perm, (float*)d_out, N);
}

// Round 3
// 905.505 us; speedup vs baseline: 10.5894x; 1.4133x over previous
//
#include <hip/hip_runtime.h>
#include <math.h>

// ================= GEMM: P[n,512] = X[n,128] @ {Wq,Wk,Wv,Ws} + biases =================
// k' and v' columns also get +be (exact folding of the edge-embedding bias).
__global__ __launch_bounds__(256) void gemm_proj(
    const float* __restrict__ X, int M,
    const float* __restrict__ Wq, const float* __restrict__ bq,
    const float* __restrict__ Wk, const float* __restrict__ bk,
    const float* __restrict__ Wv, const float* __restrict__ bv,
    const float* __restrict__ Ws, const float* __restrict__ bs,
    const float* __restrict__ be,
    float* __restrict__ P)
{
    __shared__ float As[128][64];   // As[k][row]
    __shared__ float Bs[128][64];   // Bs[k][col]
    const int tid = threadIdx.x;
    const int row0 = blockIdx.x * 64;
    const int col0 = blockIdx.y * 64;          // global col in [0,512)
    const int sel = col0 >> 7;
    const int wc0 = col0 & 127;
    const float* W; const float* B;
    if (sel == 0)      { W = Wq; B = bq; }
    else if (sel == 1) { W = Wk; B = bk; }
    else if (sel == 2) { W = Wv; B = bv; }
    else               { W = Ws; B = bs; }
    const bool add_be = (sel == 1 || sel == 2);

#pragma unroll
    for (int u = 0; u < 8; ++u) {
        int flat = tid * 32 + u * 4;
        int r = flat >> 7, k = flat & 127;
        float4 v = make_float4(0.f, 0.f, 0.f, 0.f);
        if (row0 + r < M) v = *(const float4*)(X + (size_t)(row0 + r) * 128 + k);
        As[k + 0][r] = v.x; As[k + 1][r] = v.y; As[k + 2][r] = v.z; As[k + 3][r] = v.w;
    }
#pragma unroll
    for (int u = 0; u < 8; ++u) {
        int flat = tid * 32 + u * 4;
        int k = flat >> 6, c = flat & 63;
        *(float4*)(&Bs[k][c]) = *(const float4*)(W + k * 128 + wc0 + c);
    }
    __syncthreads();

    const int tx = tid & 15, ty = tid >> 4;
    const int r0 = ty * 4, c0 = tx * 4;
    float acc[4][4] = {};
#pragma unroll 8
    for (int k = 0; k < 128; ++k) {
        float4 a = *(const float4*)(&As[k][r0]);
        float4 b = *(const float4*)(&Bs[k][c0]);
        acc[0][0] += a.x * b.x; acc[0][1] += a.x * b.y; acc[0][2] += a.x * b.z; acc[0][3] += a.x * b.w;
        acc[1][0] += a.y * b.x; acc[1][1] += a.y * b.y; acc[1][2] += a.y * b.z; acc[1][3] += a.y * b.w;
        acc[2][0] += a.z * b.x; acc[2][1] += a.z * b.y; acc[2][2] += a.z * b.z; acc[2][3] += a.z * b.w;
        acc[3][0] += a.w * b.x; acc[3][1] += a.w * b.y; acc[3][2] += a.w * b.z; acc[3][3] += a.w * b.w;
    }
    float bias[4];
#pragma unroll
    for (int j = 0; j < 4; ++j) {
        int wc = wc0 + c0 + j;
        bias[j] = B[wc] + (add_be ? be[wc] : 0.f);
    }
#pragma unroll
    for (int i = 0; i < 4; ++i) {
        int gr = row0 + r0 + i;
        if (gr < M) {
            float4 o;
            o.x = acc[i][0] + bias[0];
            o.y = acc[i][1] + bias[1];
            o.z = acc[i][2] + bias[2];
            o.w = acc[i][3] + bias[3];
            *(float4*)(P + (size_t)gr * 512 + col0 + c0) = o;
        }
    }
}

// ================= CSR build (int atomics only) =================
__global__ __launch_bounds__(256) void degree_kernel(
    const int* __restrict__ ei, int* __restrict__ deg, int E)
{
    int e = blockIdx.x * blockDim.x + threadIdx.x;
    if (e < E) atomicAdd(&deg[ei[E + e]], 1);
}

__global__ __launch_bounds__(1024) void scan_kernel(
    const int* __restrict__ deg, int* __restrict__ rowptr,
    int* __restrict__ cursor, int N)
{
    __shared__ int tmp[1024];
    __shared__ int carry_s;
    if (threadIdx.x == 0) { carry_s = 0; rowptr[0] = 0; }
    __syncthreads();
    for (int base = 0; base < N; base += 1024) {
        int i = base + threadIdx.x;
        int v = (i < N) ? deg[i] : 0;
        tmp[threadIdx.x] = v;
        __syncthreads();
        for (int ofs = 1; ofs < 1024; ofs <<= 1) {
            int t = (threadIdx.x >= ofs) ? tmp[threadIdx.x - ofs] : 0;
            __syncthreads();
            tmp[threadIdx.x] += t;
            __syncthreads();
        }
        int carry = carry_s;
        if (i < N) {
            rowptr[i + 1] = carry + tmp[threadIdx.x];
            cursor[i]     = carry + tmp[threadIdx.x] - v;
        }
        __syncthreads();
        if (threadIdx.x == 1023) carry_s = carry + tmp[1023];
        __syncthreads();
    }
}

__global__ __launch_bounds__(256) void scatter_kernel(
    const int* __restrict__ ei, int* __restrict__ cursor,
    int* __restrict__ perm, int E)
{
    int e = blockIdx.x * blockDim.x + threadIdx.x;
    if (e < E) {
        int pos = atomicAdd(&cursor[ei[E + e]], 1);
        perm[pos] = e;
    }
}

// ================= qWe precompute =================
// layer1: qWe[n, h, k] = sum_c q[n,h,c] * We1[k, h*16+c]
__global__ __launch_bounds__(256) void qwe1_kernel(
    const float* __restrict__ P, const float* __restrict__ We1,
    float* __restrict__ qWe, int N)
{
    int g = blockIdx.x * blockDim.x + threadIdx.x;
    if (g >= N * 128) return;
    int n = g >> 7, rem = g & 127, h = rem >> 4, k = rem & 15;
    const float* q = P + (size_t)n * 512 + h * 16;
    const float* w = We1 + k * 128 + h * 16;
    float s = 0.f;
#pragma unroll
    for (int c = 0; c < 16; ++c) s += q[c] * w[c];
    qWe[g] = s;
}

// layer2: qWe[n, k] = sum_c q[n,c] * We2[k, c]
__global__ __launch_bounds__(256) void qwe2_kernel(
    const float* __restrict__ P, const float* __restrict__ We2,
    float* __restrict__ qWe, int N)
{
    int g = blockIdx.x * blockDim.x + threadIdx.x;
    if (g >= N * 16) return;
    int n = g >> 4, k = g & 15;
    const float4* q = (const float4*)(P + (size_t)n * 512);
    const float4* w = (const float4*)(We2 + (size_t)k * 128);
    float s = 0.f;
#pragma unroll
    for (int i = 0; i < 32; ++i) {
        float4 a = q[i], b = w[i];
        s += a.x * b.x + a.y * b.y + a.z * b.z + a.w * b.w;
    }
    qWe[g] = s;
}

// ================= fused score + online-softmax + aggregation =================
// Layer 1: H=8, C=16. One wave per node; lane covers channels (2*lane, 2*lane+1)
// of head h = lane>>3 (sub = lane&7). Chunks of 8 edges with online-softmax
// rescaling (correct for any degree). Edge-embedding contribution via the
// per-head accumulator A_h[k] = sum_e w_e * ea[e][k], expanded through We1 once
// per node in the epilogue (2 FMA/lane/edge instead of 32).
__global__ __launch_bounds__(256) void fused1_node(
    const float* __restrict__ P, const float* __restrict__ qWe,
    const float* __restrict__ ea, const float* __restrict__ We1,
    const int* __restrict__ ei, const int* __restrict__ rowptr,
    const int* __restrict__ perm, float* __restrict__ h1, int N)
{
    const int lane = threadIdx.x & 63;
    const int node = blockIdx.x * 4 + (threadIdx.x >> 6);
    if (node >= N) return;
    const int beg = rowptr[node];
    const int deg = rowptr[node + 1] - beg;
    const int h = lane >> 3, sub = lane & 7;
    const int c0 = lane * 2;

    float2 skip = *(const float2*)(P + (size_t)node * 512 + 384 + c0);
    float* outp = h1 + (size_t)node * 128 + c0;
    if (deg == 0) {
        outp[0] = skip.x > 0.f ? skip.x : 0.01f * skip.x;
        outp[1] = skip.y > 0.f ? skip.y : 0.01f * skip.y;
        return;
    }

    float2 q2  = *(const float2*)(P + (size_t)node * 512 + c0);
    float2 qw2 = *(const float2*)(qWe + (size_t)node * 128 + c0);

    float2 acc = make_float2(0.f, 0.f);
    float2 A2  = make_float2(0.f, 0.f);
    float m = -INFINITY, lden = 0.f;

    for (int base = 0; base < deg; base += 8) {
        const int cnt = min(8, deg - base);
        int e = 0, src = 0;
        if (lane < cnt) { e = perm[beg + base + lane]; src = ei[e]; }

        float2 v2s[8], eas[8];
        float my_s = -INFINITY;
#pragma unroll
        for (int i = 0; i < 8; ++i) {
            if (i < cnt) {  // wave-uniform
                int sb = __shfl(src, i, 64);
                int eb = __shfl(e, i, 64);
                const float* rowp = P + (size_t)sb * 512;
                float2 k2 = *(const float2*)(rowp + 128 + c0);
                v2s[i]    = *(const float2*)(rowp + 256 + c0);
                float2 e2 = *(const float2*)(ea + (size_t)eb * 16 + sub * 2);
                eas[i] = e2;
                float p = q2.x * k2.x + q2.y * k2.y + qw2.x * e2.x + qw2.y * e2.y;
                p += __shfl_xor(p, 1, 64);
                p += __shfl_xor(p, 2, 64);
                p += __shfl_xor(p, 4, 64);   // per-head dot in each 8-lane group
                if (sub == i) my_s = p * 0.25f;  // 1/sqrt(16)
            } else {
                v2s[i] = make_float2(0.f, 0.f);
                eas[i] = make_float2(0.f, 0.f);
            }
        }
        // per-head chunk max
        float cm = my_s;
        cm = fmaxf(cm, __shfl_xor(cm, 1, 64));
        cm = fmaxf(cm, __shfl_xor(cm, 2, 64));
        cm = fmaxf(cm, __shfl_xor(cm, 4, 64));
        float m_new = fmaxf(m, cm);
        float scale = __expf(m - m_new);       // first chunk: exp(-inf)=0
        float ew = (sub < cnt) ? __expf(my_s - m_new) : 0.f;
        float ds = ew;
        ds += __shfl_xor(ds, 1, 64);
        ds += __shfl_xor(ds, 2, 64);
        ds += __shfl_xor(ds, 4, 64);
        lden = lden * scale + ds;
        acc.x *= scale; acc.y *= scale;
        A2.x  *= scale; A2.y  *= scale;
        m = m_new;
#pragma unroll
        for (int i = 0; i < 8; ++i) {
            float w = __shfl(ew, (h << 3) | i, 64);  // 0 for padded slots
            acc.x += w * v2s[i].x; acc.y += w * v2s[i].y;
            A2.x  += w * eas[i].x; A2.y  += w * eas[i].y;
        }
    }

    // epilogue: expand A_h through We1, normalize, skip, leaky-relu
    float ex = 0.f, ey = 0.f;
#pragma unroll
    for (int k = 0; k < 8; ++k) {
        float ax = __shfl(A2.x, (h << 3) | k, 64);  // A_h[2k]
        float ay = __shfl(A2.y, (h << 3) | k, 64);  // A_h[2k+1]
        float2 w0 = *(const float2*)(We1 + (2 * k) * 128 + c0);
        float2 w1 = *(const float2*)(We1 + (2 * k + 1) * 128 + c0);
        ex += ax * w0.x + ay * w1.x;
        ey += ax * w0.y + ay * w1.y;
    }
    float inv = 1.f / (lden + 1e-16f);
    float s0 = (acc.x + ex) * inv + skip.x;
    float s1 = (acc.y + ey) * inv + skip.y;
    outp[0] = s0 > 0.f ? s0 : 0.01f * s0;
    outp[1] = s1 > 0.f ? s1 : 0.01f * s1;
}

// Layer 2: H=1, C=128. Full-wave dot per edge; same online-softmax chunking.
__global__ __launch_bounds__(256) void fused2_node(
    const float* __restrict__ P, const float* __restrict__ qWe,
    const float* __restrict__ ea, const float* __restrict__ We2,
    const int* __restrict__ ei, const int* __restrict__ rowptr,
    const int* __restrict__ perm, float* __restrict__ out, int N)
{
    const int lane = threadIdx.x & 63;
    const int node = blockIdx.x * 4 + (threadIdx.x >> 6);
    if (node >= N) return;
    const int beg = rowptr[node];
    const int deg = rowptr[node + 1] - beg;
    const int c0 = lane * 2;
    const int k16 = lane & 15;

    float2 skip = *(const float2*)(P + (size_t)node * 512 + 384 + c0);
    float* outp = out + (size_t)node * 128 + c0;
    if (deg == 0) { outp[0] = skip.x; outp[1] = skip.y; return; }

    float2 q2 = *(const float2*)(P + (size_t)node * 512 + c0);
    float  qw = qWe[(size_t)node * 16 + k16];

    float2 acc = make_float2(0.f, 0.f);
    float  accA = 0.f;   // A[k16], 4 identical copies across lane quarters
    float m = -INFINITY, lden = 0.f;

    for (int base = 0; base < deg; base += 8) {
        const int cnt = min(8, deg - base);
        int e = 0, src = 0;
        if (lane < cnt) { e = perm[beg + base + lane]; src = ei[e]; }

        float2 v2s[8]; float eas[8];
        float my_s = -INFINITY;
#pragma unroll
        for (int i = 0; i < 8; ++i) {
            if (i < cnt) {  // wave-uniform
                int sb = __shfl(src, i, 64);
                int eb = __shfl(e, i, 64);
                const float* rowp = P + (size_t)sb * 512;
                float2 k2 = *(const float2*)(rowp + 128 + c0);
                v2s[i]    = *(const float2*)(rowp + 256 + c0);
                float eav = ea[(size_t)eb * 16 + k16];
                eas[i] = eav;
                // 64 lanes duplicate the 16-elem ea-dot 4x -> scale by 0.25
                float p = q2.x * k2.x + q2.y * k2.y + 0.25f * qw * eav;
                p += __shfl_xor(p, 1, 64);
                p += __shfl_xor(p, 2, 64);
                p += __shfl_xor(p, 4, 64);
                p += __shfl_xor(p, 8, 64);
                p += __shfl_xor(p, 16, 64);
                p += __shfl_xor(p, 32, 64);
                if (lane == i) my_s = p * 0.08838834764831845f;  // 1/sqrt(128)
            } else {
                v2s[i] = make_float2(0.f, 0.f);
                eas[i] = 0.f;
            }
        }
        float cm = my_s;
#pragma unroll
        for (int mk = 1; mk < 64; mk <<= 1) cm = fmaxf(cm, __shfl_xor(cm, mk, 64));
        float m_new = fmaxf(m, cm);
        float scale = __expf(m - m_new);
        float ew = (lane < cnt) ? __expf(my_s - m_new) : 0.f;
        float ds = ew;
#pragma unroll
        for (int mk = 1; mk < 64; mk <<= 1) ds += __shfl_xor(ds, mk, 64);
        lden = lden * scale + ds;
        acc.x *= scale; acc.y *= scale; accA *= scale;
        m = m_new;
#pragma unroll
        for (int i = 0; i < 8; ++i) {
            float w = __shfl(ew, i, 64);  // 0 for padded slots
            acc.x += w * v2s[i].x; acc.y += w * v2s[i].y;
            accA  += w * eas[i];
        }
    }

    // epilogue: expand A through We2, normalize, add skip
    float ex = 0.f, ey = 0.f;
#pragma unroll
    for (int k = 0; k < 16; ++k) {
        float ak = __shfl(accA, (lane & 48) | k, 64);
        float2 w2 = *(const float2*)(We2 + k * 128 + c0);
        ex += ak * w2.x;
        ey += ak * w2.y;
    }
    float inv = 1.f / (lden + 1e-16f);
    outp[0] = (acc.x + ex) * inv + skip.x;
    outp[1] = (acc.y + ey) * inv + skip.y;
}

// ================= launch =================
extern "C" void kernel_launch(void* const* d_in, const int* in_sizes, int n_in,
                              void* d_out, int out_size, void* d_ws, size_t ws_size,
                              hipStream_t stream)
{
    const float* x  = (const float*)d_in[0];
    const int*   ei = (const int*)d_in[1];
    const float* ea = (const float*)d_in[2];
    const float *Wq1 = (const float*)d_in[3],  *bq1 = (const float*)d_in[4];
    const float *Wk1 = (const float*)d_in[5],  *bk1 = (const float*)d_in[6];
    const float *Wv1 = (const float*)d_in[7],  *bv1 = (const float*)d_in[8];
    const float *We1 = (const float*)d_in[9],  *be1 = (const float*)d_in[10];
    const float *Ws1 = (const float*)d_in[11], *bs1 = (const float*)d_in[12];
    const float *Wq2 = (const float*)d_in[13], *bq2 = (const float*)d_in[14];
    const float *Wk2 = (const float*)d_in[15], *bk2 = (const float*)d_in[16];
    const float *Wv2 = (const float*)d_in[17], *bv2 = (const float*)d_in[18];
    const float *We2 = (const float*)d_in[19], *be2 = (const float*)d_in[20];
    const float *Ws2 = (const float*)d_in[21], *bs2 = (const float*)d_in[22];

    const int N = in_sizes[0] / 128;
    const int E = in_sizes[1] / 2;

    char* ws = (char*)d_ws;
    size_t off = 0;
    auto alloc = [&](size_t bytes) -> void* {
        void* p = ws + off;
        off = (off + bytes + 255) & ~(size_t)255;
        return p;
    };
    float* P      = (float*)alloc((size_t)N * 512 * 4);  // q | k'+be | v'+be | s
    float* qWe    = (float*)alloc((size_t)N * 128 * 4);
    float* h1     = (float*)alloc((size_t)N * 128 * 4);
    int*   deg    = (int*)alloc((size_t)N * 4);
    int*   rowptr = (int*)alloc((size_t)(N + 1) * 4);
    int*   cursor = (int*)alloc((size_t)N * 4);
    int*   perm   = (int*)alloc((size_t)E * 4);

    dim3 gemm_grid((N + 63) / 64, 8);
    const int tn = N * 128;
    const int node_blocks = (N + 3) / 4;

    // ---- CSR build (shared by both layers) ----
    hipMemsetAsync(deg, 0, (size_t)N * 4, stream);
    degree_kernel<<<(E + 255) / 256, 256, 0, stream>>>(ei, deg, E);
    scan_kernel<<<1, 1024, 0, stream>>>(deg, rowptr, cursor, N);
    scatter_kernel<<<(E + 255) / 256, 256, 0, stream>>>(ei, cursor, perm, E);

    // ---- layer 1 (H=8, C=16, concat) ----
    gemm_proj<<<gemm_grid, 256, 0, stream>>>(x, N, Wq1, bq1, Wk1, bk1, Wv1, bv1, Ws1, bs1, be1, P);
    qwe1_kernel<<<(tn + 255) / 256, 256, 0, stream>>>(P, We1, qWe, N);
    fused1_node<<<node_blocks, 256, 0, stream>>>(P, qWe, ea, We1, ei, rowptr, perm, h1, N);

    // ---- layer 2 (H=1, C=128, mean==identity) ----
    gemm_proj<<<gemm_grid, 256, 0, stream>>>(h1, N, Wq2, bq2, Wk2, bk2, Wv2, bv2, Ws2, bs2, be2, P);
    qwe2_kernel<<<(N * 16 + 255) / 256, 256, 0, stream>>>(P, We2, qWe, N);
    fused2_node<<<node_blocks, 256, 0, stream>>>(P, qWe, ea, We2, ei, rowptr, perm, (float*)d_out, N);
}

// Round 4
// 808.202 us; speedup vs baseline: 11.8643x; 1.1204x over previous
//
#include <hip/hip_runtime.h>
#include <math.h>

typedef __bf16 bf16x8 __attribute__((ext_vector_type(8)));
typedef float f32x4 __attribute__((ext_vector_type(4)));

// ---------------- bf16 helpers (manual RNE, no header type friction) ----------------
__device__ __forceinline__ unsigned short f2bf(float f) {
    unsigned u = __float_as_uint(f);
    return (unsigned short)((u + 0x7fffu + ((u >> 16) & 1u)) >> 16);
}
__device__ __forceinline__ float2 bf2(unsigned u) {  // two packed bf16 -> two floats
    float2 r;
    r.x = __uint_as_float(u << 16);
    r.y = __uint_as_float(u & 0xffff0000u);
    return r;
}

// ---------------- prep: x -> bf16 ----------------
__global__ __launch_bounds__(256) void convert_x(
    const float* __restrict__ x, unsigned short* __restrict__ xb, int total)
{
    int g = blockIdx.x * blockDim.x + threadIdx.x;
    if (g < total) xb[g] = f2bf(x[g]);
}

// ---------------- prep: transposed bf16 weights + folded bias ----------------
// P column layout: [0,128)=k'(Wk,bk+be) [128,256)=v'(Wv,bv+be) [256,384)=q(Wq,bq) [384,512)=s(Ws,bs)
// Wt[c][k] = W_sel[k][c&127]  (so MFMA B-fragments are 16B-contiguous along k)
__global__ __launch_bounds__(256) void prep_w(
    const float* __restrict__ Wq, const float* __restrict__ bq,
    const float* __restrict__ Wk, const float* __restrict__ bk,
    const float* __restrict__ Wv, const float* __restrict__ bv,
    const float* __restrict__ be,
    const float* __restrict__ Ws, const float* __restrict__ bs,
    unsigned short* __restrict__ Wt, float* __restrict__ bias)
{
    int g = blockIdx.x * blockDim.x + threadIdx.x;
    if (g < 512) {
        int c = g & 127;
        float b;
        if (g < 128)      b = bk[c] + be[c];
        else if (g < 256) b = bv[c] + be[c];
        else if (g < 384) b = bq[c];
        else              b = bs[c];
        bias[g] = b;
    }
    if (g >= 512 * 128) return;
    int c = g >> 7, k = g & 127, cc = c & 127;
    const float* W = (c < 128) ? Wk : (c < 256) ? Wv : (c < 384) ? Wq : Ws;
    Wt[(size_t)c * 128 + k] = f2bf(W[k * 128 + cc]);
}

// ---------------- MFMA bf16 GEMM: P[m,512] = Xb[m,128] @ W + bias ----------------
// block = 4 waves; wave w covers rows [bx*64+w*16, +16) x cols [by*64, +64).
// A-frag: lane: m=l&15, k=(l>>4)*8+j (16B contiguous from Xb).
// B-frag: lane: n=l&15, k=(l>>4)*8+j (16B contiguous from Wt, L2-hot).
// C-frag: col=lane&15, row=(lane>>4)*4+reg  [measured: learn_hip m89/m91]
__global__ __launch_bounds__(256) void gemm_bf16(
    const unsigned short* __restrict__ Xb, int M,
    const unsigned short* __restrict__ Wt, const float* __restrict__ bias,
    unsigned short* __restrict__ P)
{
    const int wv = threadIdx.x >> 6, lane = threadIdx.x & 63;
    const int row0 = blockIdx.x * 64 + wv * 16;
    const int n0 = blockIdx.y * 64;
    const int quad = lane >> 4, l16 = lane & 15;

    f32x4 acc[4] = {};
    int mrow = row0 + l16; if (mrow >= M) mrow = M - 1;  // clamp loads; stores guarded
    const int kb = quad * 8;
#pragma unroll
    for (int kk = 0; kk < 4; ++kk) {
        bf16x8 a = *(const bf16x8*)(Xb + (size_t)mrow * 128 + kk * 32 + kb);
#pragma unroll
        for (int f = 0; f < 4; ++f) {
            bf16x8 b = *(const bf16x8*)(Wt + (size_t)(n0 + f * 16 + l16) * 128 + kk * 32 + kb);
            acc[f] = __builtin_amdgcn_mfma_f32_16x16x32_bf16(a, b, acc[f], 0, 0, 0);
        }
    }
#pragma unroll
    for (int f = 0; f < 4; ++f) {
        int c = n0 + f * 16 + l16;
        float bs = bias[c];
#pragma unroll
        for (int r = 0; r < 4; ++r) {
            int m = row0 + quad * 4 + r;
            if (m < M) P[(size_t)m * 512 + c] = f2bf(acc[f][r] + bs);
        }
    }
}

// ---------------- CSR build (int atomics only) ----------------
__global__ __launch_bounds__(256) void degree_kernel(
    const int* __restrict__ ei, int* __restrict__ deg, int E)
{
    int e = blockIdx.x * blockDim.x + threadIdx.x;
    if (e < E) atomicAdd(&deg[ei[E + e]], 1);
}

__global__ __launch_bounds__(1024) void scan_kernel(
    const int* __restrict__ deg, int* __restrict__ rowptr,
    int* __restrict__ cursor, int N)
{
    __shared__ int tmp[1024];
    __shared__ int carry_s;
    if (threadIdx.x == 0) { carry_s = 0; rowptr[0] = 0; }
    __syncthreads();
    for (int base = 0; base < N; base += 1024) {
        int i = base + threadIdx.x;
        int v = (i < N) ? deg[i] : 0;
        tmp[threadIdx.x] = v;
        __syncthreads();
        for (int ofs = 1; ofs < 1024; ofs <<= 1) {
            int t = (threadIdx.x >= ofs) ? tmp[threadIdx.x - ofs] : 0;
            __syncthreads();
            tmp[threadIdx.x] += t;
            __syncthreads();
        }
        int carry = carry_s;
        if (i < N) {
            rowptr[i + 1] = carry + tmp[threadIdx.x];
            cursor[i]     = carry + tmp[threadIdx.x] - v;
        }
        __syncthreads();
        if (threadIdx.x == 1023) carry_s = carry + tmp[1023];
        __syncthreads();
    }
}

__global__ __launch_bounds__(256) void scatter_kernel(
    const int* __restrict__ ei, int* __restrict__ cursor,
    int* __restrict__ perm, int E)
{
    int e = blockIdx.x * blockDim.x + threadIdx.x;
    if (e < E) {
        int pos = atomicAdd(&cursor[ei[E + e]], 1);
        perm[pos] = e;
    }
}

// ---------------- qWe precompute (bf16 q) ----------------
// layer1: qWe[n, h, k] = sum_c q[n,h,c] * We1[k, h*16+c]
__global__ __launch_bounds__(256) void qwe1_kernel(
    const unsigned short* __restrict__ P, const float* __restrict__ We1,
    float* __restrict__ qWe, int N)
{
    int g = blockIdx.x * blockDim.x + threadIdx.x;
    if (g >= N * 128) return;
    int n = g >> 7, rem = g & 127, h = rem >> 4, k = rem & 15;
    const unsigned* qu = (const unsigned*)(P + (size_t)n * 512 + 256 + h * 16);
    const float* w = We1 + k * 128 + h * 16;
    float s = 0.f;
#pragma unroll
    for (int i = 0; i < 8; ++i) {
        float2 q2 = bf2(qu[i]);
        s += q2.x * w[2 * i] + q2.y * w[2 * i + 1];
    }
    qWe[g] = s;
}

// layer2: qWe[n, k] = sum_c q[n,c] * We2[k, c]
__global__ __launch_bounds__(256) void qwe2_kernel(
    const unsigned short* __restrict__ P, const float* __restrict__ We2,
    float* __restrict__ qWe, int N)
{
    int g = blockIdx.x * blockDim.x + threadIdx.x;
    if (g >= N * 16) return;
    int n = g >> 4, k = g & 15;
    const unsigned* qu = (const unsigned*)(P + (size_t)n * 512 + 256);
    const float* w = We2 + (size_t)k * 128;
    float s = 0.f;
#pragma unroll
    for (int i = 0; i < 64; ++i) {
        float2 q2 = bf2(qu[i]);
        s += q2.x * w[2 * i] + q2.y * w[2 * i + 1];
    }
    qWe[g] = s;
}

// ---------------- fused score + online-softmax + aggregation ----------------
// Layer 1: H=8, C=16. One wave/node; lane covers channels (2*lane, 2*lane+1) of
// head h=lane>>3. 8-edge chunks, online softmax. Edge-embed contribution via
// per-head accumulator expanded through We1 in the epilogue.
__global__ __launch_bounds__(256) void fused1_node(
    const unsigned short* __restrict__ P, const float* __restrict__ qWe,
    const float* __restrict__ ea, const float* __restrict__ We1,
    const int* __restrict__ ei, const int* __restrict__ rowptr,
    const int* __restrict__ perm, unsigned short* __restrict__ h1, int N)
{
    const int lane = threadIdx.x & 63;
    const int node = blockIdx.x * 4 + (threadIdx.x >> 6);
    if (node >= N) return;
    const int beg = rowptr[node];
    const int deg = rowptr[node + 1] - beg;
    const int h = lane >> 3, sub = lane & 7;
    const int c0 = lane * 2;

    float2 skip = bf2(*(const unsigned*)(P + (size_t)node * 512 + 384 + c0));
    unsigned* outp = (unsigned*)(h1 + (size_t)node * 128 + c0);
    if (deg == 0) {
        float s0 = skip.x > 0.f ? skip.x : 0.01f * skip.x;
        float s1 = skip.y > 0.f ? skip.y : 0.01f * skip.y;
        *outp = (unsigned)f2bf(s0) | ((unsigned)f2bf(s1) << 16);
        return;
    }

    float2 q2  = bf2(*(const unsigned*)(P + (size_t)node * 512 + 256 + c0));
    float2 qw2 = *(const float2*)(qWe + (size_t)node * 128 + c0);

    float2 acc = make_float2(0.f, 0.f);
    float2 A2  = make_float2(0.f, 0.f);
    float m = -INFINITY, lden = 0.f;

    for (int base = 0; base < deg; base += 8) {
        const int cnt = min(8, deg - base);
        int e = 0, src = 0;
        if (lane < cnt) { e = perm[beg + base + lane]; src = ei[e]; }

        float2 v2s[8], eas[8];
        float my_s = -INFINITY;
#pragma unroll
        for (int i = 0; i < 8; ++i) {
            if (i < cnt) {  // wave-uniform
                int sb = __shfl(src, i, 64);
                int eb = __shfl(e, i, 64);
                const unsigned short* rowp = P + (size_t)sb * 512;
                float2 k2 = bf2(*(const unsigned*)(rowp + c0));        // k'
                v2s[i]    = bf2(*(const unsigned*)(rowp + 128 + c0));  // v'
                float2 e2 = *(const float2*)(ea + (size_t)eb * 16 + sub * 2);
                eas[i] = e2;
                float p = q2.x * k2.x + q2.y * k2.y + qw2.x * e2.x + qw2.y * e2.y;
                p += __shfl_xor(p, 1, 64);
                p += __shfl_xor(p, 2, 64);
                p += __shfl_xor(p, 4, 64);   // per-head dot within 8-lane group
                if (sub == i) my_s = p * 0.25f;  // 1/sqrt(16)
            } else {
                v2s[i] = make_float2(0.f, 0.f);
                eas[i] = make_float2(0.f, 0.f);
            }
        }
        float cm = my_s;
        cm = fmaxf(cm, __shfl_xor(cm, 1, 64));
        cm = fmaxf(cm, __shfl_xor(cm, 2, 64));
        cm = fmaxf(cm, __shfl_xor(cm, 4, 64));
        float m_new = fmaxf(m, cm);
        float scale = __expf(m - m_new);       // first chunk: exp(-inf)=0
        float ew = (sub < cnt) ? __expf(my_s - m_new) : 0.f;
        float ds = ew;
        ds += __shfl_xor(ds, 1, 64);
        ds += __shfl_xor(ds, 2, 64);
        ds += __shfl_xor(ds, 4, 64);
        lden = lden * scale + ds;
        acc.x *= scale; acc.y *= scale;
        A2.x  *= scale; A2.y  *= scale;
        m = m_new;
#pragma unroll
        for (int i = 0; i < 8; ++i) {
            float w = __shfl(ew, (h << 3) | i, 64);  // 0 for padded slots
            acc.x += w * v2s[i].x; acc.y += w * v2s[i].y;
            A2.x  += w * eas[i].x; A2.y  += w * eas[i].y;
        }
    }

    float ex = 0.f, ey = 0.f;
#pragma unroll
    for (int k = 0; k < 8; ++k) {
        float ax = __shfl(A2.x, (h << 3) | k, 64);
        float ay = __shfl(A2.y, (h << 3) | k, 64);
        float2 w0 = *(const float2*)(We1 + (2 * k) * 128 + c0);
        float2 w1 = *(const float2*)(We1 + (2 * k + 1) * 128 + c0);
        ex += ax * w0.x + ay * w1.x;
        ey += ax * w0.y + ay * w1.y;
    }
    float inv = 1.f / (lden + 1e-16f);
    float s0 = (acc.x + ex) * inv + skip.x;
    float s1 = (acc.y + ey) * inv + skip.y;
    s0 = s0 > 0.f ? s0 : 0.01f * s0;
    s1 = s1 > 0.f ? s1 : 0.01f * s1;
    *outp = (unsigned)f2bf(s0) | ((unsigned)f2bf(s1) << 16);
}

// Layer 2: H=1, C=128.
__global__ __launch_bounds__(256) void fused2_node(
    const unsigned short* __restrict__ P, const float* __restrict__ qWe,
    const float* __restrict__ ea, const float* __restrict__ We2,
    const int* __restrict__ ei, const int* __restrict__ rowptr,
    const int* __restrict__ perm, float* __restrict__ out, int N)
{
    const int lane = threadIdx.x & 63;
    const int node = blockIdx.x * 4 + (threadIdx.x >> 6);
    if (node >= N) return;
    const int beg = rowptr[node];
    const int deg = rowptr[node + 1] - beg;
    const int c0 = lane * 2;
    const int k16 = lane & 15;

    float2 skip = bf2(*(const unsigned*)(P + (size_t)node * 512 + 384 + c0));
    float* outp = out + (size_t)node * 128 + c0;
    if (deg == 0) { outp[0] = skip.x; outp[1] = skip.y; return; }

    float2 q2 = bf2(*(const unsigned*)(P + (size_t)node * 512 + 256 + c0));
    float  qw = qWe[(size_t)node * 16 + k16];

    float2 acc = make_float2(0.f, 0.f);
    float  accA = 0.f;   // A[k16], 4 copies across lane quarters
    float m = -INFINITY, lden = 0.f;

    for (int base = 0; base < deg; base += 8) {
        const int cnt = min(8, deg - base);
        int e = 0, src = 0;
        if (lane < cnt) { e = perm[beg + base + lane]; src = ei[e]; }

        float2 v2s[8]; float eas[8];
        float my_s = -INFINITY;
#pragma unroll
        for (int i = 0; i < 8; ++i) {
            if (i < cnt) {  // wave-uniform
                int sb = __shfl(src, i, 64);
                int eb = __shfl(e, i, 64);
                const unsigned short* rowp = P + (size_t)sb * 512;
                float2 k2 = bf2(*(const unsigned*)(rowp + c0));
                v2s[i]    = bf2(*(const unsigned*)(rowp + 128 + c0));
                float eav = ea[(size_t)eb * 16 + k16];
                eas[i] = eav;
                float p = q2.x * k2.x + q2.y * k2.y + 0.25f * qw * eav;  // ea-dot 4x dup
                p += __shfl_xor(p, 1, 64);
                p += __shfl_xor(p, 2, 64);
                p += __shfl_xor(p, 4, 64);
                p += __shfl_xor(p, 8, 64);
                p += __shfl_xor(p, 16, 64);
                p += __shfl_xor(p, 32, 64);
                if (lane == i) my_s = p * 0.08838834764831845f;  // 1/sqrt(128)
            } else {
                v2s[i] = make_float2(0.f, 0.f);
                eas[i] = 0.f;
            }
        }
        float cm = my_s;
#pragma unroll
        for (int mk = 1; mk < 64; mk <<= 1) cm = fmaxf(cm, __shfl_xor(cm, mk, 64));
        float m_new = fmaxf(m, cm);
        float scale = __expf(m - m_new);
        float ew = (lane < cnt) ? __expf(my_s - m_new) : 0.f;
        float ds = ew;
#pragma unroll
        for (int mk = 1; mk < 64; mk <<= 1) ds += __shfl_xor(ds, mk, 64);
        lden = lden * scale + ds;
        acc.x *= scale; acc.y *= scale; accA *= scale;
        m = m_new;
#pragma unroll
        for (int i = 0; i < 8; ++i) {
            float w = __shfl(ew, i, 64);
            acc.x += w * v2s[i].x; acc.y += w * v2s[i].y;
            accA  += w * eas[i];
        }
    }

    float ex = 0.f, ey = 0.f;
#pragma unroll
    for (int k = 0; k < 16; ++k) {
        float ak = __shfl(accA, (lane & 48) | k, 64);
        float2 w2 = *(const float2*)(We2 + k * 128 + c0);
        ex += ak * w2.x;
        ey += ak * w2.y;
    }
    float inv = 1.f / (lden + 1e-16f);
    outp[0] = (acc.x + ex) * inv + skip.x;
    outp[1] = (acc.y + ey) * inv + skip.y;
}

// ---------------- launch ----------------
extern "C" void kernel_launch(void* const* d_in, const int* in_sizes, int n_in,
                              void* d_out, int out_size, void* d_ws, size_t ws_size,
                              hipStream_t stream)
{
    const float* x  = (const float*)d_in[0];
    const int*   ei = (const int*)d_in[1];
    const float* ea = (const float*)d_in[2];
    const float *Wq1 = (const float*)d_in[3],  *bq1 = (const float*)d_in[4];
    const float *Wk1 = (const float*)d_in[5],  *bk1 = (const float*)d_in[6];
    const float *Wv1 = (const float*)d_in[7],  *bv1 = (const float*)d_in[8];
    const float *We1 = (const float*)d_in[9],  *be1 = (const float*)d_in[10];
    const float *Ws1 = (const float*)d_in[11], *bs1 = (const float*)d_in[12];
    const float *Wq2 = (const float*)d_in[13], *bq2 = (const float*)d_in[14];
    const float *Wk2 = (const float*)d_in[15], *bk2 = (const float*)d_in[16];
    const float *Wv2 = (const float*)d_in[17], *bv2 = (const float*)d_in[18];
    const float *We2 = (const float*)d_in[19], *be2 = (const float*)d_in[20];
    const float *Ws2 = (const float*)d_in[21], *bs2 = (const float*)d_in[22];

    const int N = in_sizes[0] / 128;
    const int E = in_sizes[1] / 2;

    char* ws = (char*)d_ws;
    size_t off = 0;
    auto alloc = [&](size_t bytes) -> void* {
        void* p = ws + off;
        off = (off + bytes + 255) & ~(size_t)255;
        return p;
    };
    unsigned short* xb   = (unsigned short*)alloc((size_t)N * 128 * 2);
    unsigned short* P    = (unsigned short*)alloc((size_t)N * 512 * 2);  // bf16 [k'|v'|q|s]
    unsigned short* h1b  = (unsigned short*)alloc((size_t)N * 128 * 2);
    unsigned short* Wt1  = (unsigned short*)alloc((size_t)512 * 128 * 2);
    unsigned short* Wt2  = (unsigned short*)alloc((size_t)512 * 128 * 2);
    float* bias1 = (float*)alloc(512 * 4);
    float* bias2 = (float*)alloc(512 * 4);
    float* qWe   = (float*)alloc((size_t)N * 128 * 4);
    int* deg     = (int*)alloc((size_t)N * 4);
    int* rowptr  = (int*)alloc((size_t)(N + 1) * 4);
    int* cursor  = (int*)alloc((size_t)N * 4);
    int* perm    = (int*)alloc((size_t)E * 4);

    dim3 gemm_grid((N + 63) / 64, 8);
    const int tn = N * 128;
    const int node_blocks = (N + 3) / 4;

    // ---- prep (independent of everything else) ----
    convert_x<<<(tn + 255) / 256, 256, 0, stream>>>(x, xb, tn);
    prep_w<<<256, 256, 0, stream>>>(Wq1, bq1, Wk1, bk1, Wv1, bv1, be1, Ws1, bs1, Wt1, bias1);
    prep_w<<<256, 256, 0, stream>>>(Wq2, bq2, Wk2, bk2, Wv2, bv2, be2, Ws2, bs2, Wt2, bias2);

    // ---- CSR build (shared by both layers) ----
    hipMemsetAsync(deg, 0, (size_t)N * 4, stream);
    degree_kernel<<<(E + 255) / 256, 256, 0, stream>>>(ei, deg, E);
    scan_kernel<<<1, 1024, 0, stream>>>(deg, rowptr, cursor, N);
    scatter_kernel<<<(E + 255) / 256, 256, 0, stream>>>(ei, cursor, perm, E);

    // ---- layer 1 (H=8, C=16, concat) ----
    gemm_bf16<<<gemm_grid, 256, 0, stream>>>(xb, N, Wt1, bias1, P);
    qwe1_kernel<<<(tn + 255) / 256, 256, 0, stream>>>(P, We1, qWe, N);
    fused1_node<<<node_blocks, 256, 0, stream>>>(P, qWe, ea, We1, ei, rowptr, perm, h1b, N);

    // ---- layer 2 (H=1, C=128, mean==identity) ----
    gemm_bf16<<<gemm_grid, 256, 0, stream>>>(h1b, N, Wt2, bias2, P);
    qwe2_kernel<<<(N * 16 + 255) / 256, 256, 0, stream>>>(P, We2, qWe, N);
    fused2_node<<<node_blocks, 256, 0, stream>>>(P, qWe, ea, We2, ei, rowptr, perm, (float*)d_out, N);
}

// Round 5
// 798.138 us; speedup vs baseline: 12.0139x; 1.0126x over previous
//
#include <hip/hip_runtime.h>
#include <math.h>

typedef __bf16 bf16x8 __attribute__((ext_vector_type(8)));
typedef float f32x4 __attribute__((ext_vector_type(4)));

// ---------------- bf16 helpers ----------------
__device__ __forceinline__ unsigned short f2bf(float f) {
    unsigned u = __float_as_uint(f);
    return (unsigned short)((u + 0x7fffu + ((u >> 16) & 1u)) >> 16);
}
__device__ __forceinline__ float2 bf2(unsigned u) {
    float2 r;
    r.x = __uint_as_float(u << 16);
    r.y = __uint_as_float(u & 0xffff0000u);
    return r;
}

// ---------------- prep: x -> bf16 ----------------
__global__ __launch_bounds__(256) void convert_x(
    const float* __restrict__ x, unsigned short* __restrict__ xb, int total)
{
    int g = blockIdx.x * blockDim.x + threadIdx.x;
    if (g < total) xb[g] = f2bf(x[g]);
}

// ---------------- prep: 640-col transposed bf16 weights + folded bias ----------------
// P row (bf16, 512): [0,256) interleaved k'/v' pairs: block j holds
//   (k'_{2j}, k'_{2j+1}, v'_{2j}, v'_{2j+1});  [256,384)=q;  [384,512)=s.
// Cols [512,640) of the GEMM = qWe = x @ (Wq·We^T): col 512 + h*16 + kk,
//   Wt[c][d] = sum_cc Wq[d,h*C+cc]*We[kk*128 + h*C+cc]  (0 for h>=H).
__global__ __launch_bounds__(256) void prep_w(
    const float* __restrict__ Wq, const float* __restrict__ bq,
    const float* __restrict__ Wk, const float* __restrict__ bk,
    const float* __restrict__ Wv, const float* __restrict__ bv,
    const float* __restrict__ be,
    const float* __restrict__ Ws, const float* __restrict__ bs,
    const float* __restrict__ We, int H,
    unsigned short* __restrict__ Wt, float* __restrict__ bias)
{
    int g = blockIdx.x * blockDim.x + threadIdx.x;
    const int C = 128 / H;
    if (g < 640) {
        int c = g, cc = c & 127;
        float b;
        if (c < 128)      b = bk[cc] + be[cc];
        else if (c < 256) b = bv[cc] + be[cc];
        else if (c < 384) b = bq[cc];
        else if (c < 512) b = bs[cc];
        else {
            int c2 = c - 512, h = c2 >> 4, kk = c2 & 15;
            b = 0.f;
            if (h < H) for (int i = 0; i < C; ++i) b += bq[h * C + i] * We[kk * 128 + h * C + i];
        }
        bias[c] = b;
    }
    if (g >= 640 * 128) return;
    int c = g >> 7, d = g & 127;
    float w;
    if (c < 512) {
        int cc = c & 127;
        const float* W = (c < 128) ? Wk : (c < 256) ? Wv : (c < 384) ? Wq : Ws;
        w = W[d * 128 + cc];
    } else {
        int c2 = c - 512, h = c2 >> 4, kk = c2 & 15;
        w = 0.f;
        if (h < H) for (int i = 0; i < C; ++i) w += Wq[d * 128 + h * C + i] * We[kk * 128 + h * C + i];
    }
    Wt[(size_t)c * 128 + d] = f2bf(w);
}

// ---------------- MFMA bf16 GEMM: [P | qWe] = Xb[m,128] @ Wt + bias ----------------
// C-frag: col=lane&15, row=(lane>>4)*4+reg  [measured: learn_hip m89/m91]
__global__ __launch_bounds__(256) void gemm_bf16(
    const unsigned short* __restrict__ Xb, int M,
    const unsigned short* __restrict__ Wt, const float* __restrict__ bias,
    unsigned short* __restrict__ P, float* __restrict__ qWe)
{
    const int wv = threadIdx.x >> 6, lane = threadIdx.x & 63;
    const int row0 = blockIdx.x * 64 + wv * 16;
    const int n0 = blockIdx.y * 64;                 // [0,640)
    const int quad = lane >> 4, l16 = lane & 15;

    f32x4 acc[4] = {};
    int mrow = row0 + l16; if (mrow >= M) mrow = M - 1;  // clamp loads; stores guarded
    const int kb = quad * 8;
#pragma unroll
    for (int kk = 0; kk < 4; ++kk) {
        bf16x8 a = *(const bf16x8*)(Xb + (size_t)mrow * 128 + kk * 32 + kb);
#pragma unroll
        for (int f = 0; f < 4; ++f) {
            bf16x8 b = *(const bf16x8*)(Wt + (size_t)(n0 + f * 16 + l16) * 128 + kk * 32 + kb);
            acc[f] = __builtin_amdgcn_mfma_f32_16x16x32_bf16(a, b, acc[f], 0, 0, 0);
        }
    }
#pragma unroll
    for (int f = 0; f < 4; ++f) {
        int c = n0 + f * 16 + l16;
        float bs = bias[c];
#pragma unroll
        for (int r = 0; r < 4; ++r) {
            int m = row0 + quad * 4 + r;
            if (m < M) {
                float val = acc[f][r] + bs;
                if (c < 512) {
                    int pos;
                    if (c < 256) { int cc = c & 127; pos = (cc >> 1) * 4 + ((c < 128) ? 0 : 2) + (cc & 1); }
                    else pos = c;
                    P[(size_t)m * 512 + pos] = f2bf(val);
                } else {
                    qWe[(size_t)m * 128 + (c - 512)] = val;
                }
            }
        }
    }
}

// ---------------- CSR build (int atomics only) ----------------
__global__ __launch_bounds__(256) void degree_kernel(
    const int* __restrict__ ei, int* __restrict__ deg, int E)
{
    int e = blockIdx.x * blockDim.x + threadIdx.x;
    if (e < E) atomicAdd(&deg[ei[E + e]], 1);
}

// single block: thread-serial chunks + one 1024-wide LDS scan
__global__ __launch_bounds__(1024) void scan_kernel(
    const int* __restrict__ deg, int* __restrict__ rowptr,
    int* __restrict__ cursor, int N)
{
    __shared__ int sums[1024];
    const int T = 1024;
    const int C = (N + T - 1) / T;
    const int t = threadIdx.x;
    const int b0 = t * C;
    int s = 0;
    for (int i = 0; i < C; ++i) { int idx = b0 + i; if (idx < N) s += deg[idx]; }
    sums[t] = s;
    __syncthreads();
    for (int ofs = 1; ofs < 1024; ofs <<= 1) {
        int v = (t >= ofs) ? sums[t - ofs] : 0;
        __syncthreads();
        sums[t] += v;
        __syncthreads();
    }
    int run = (t == 0) ? 0 : sums[t - 1];
    if (t == 0) rowptr[0] = 0;
    for (int i = 0; i < C; ++i) {
        int idx = b0 + i;
        if (idx < N) {
            int d = deg[idx];
            cursor[idx] = run;
            run += d;
            rowptr[idx + 1] = run;
        }
    }
}

__global__ __launch_bounds__(256) void scatter_kernel(
    const int* __restrict__ ei, int* __restrict__ cursor,
    int2* __restrict__ csr, int E)
{
    int e = blockIdx.x * blockDim.x + threadIdx.x;
    if (e < E) {
        int pos = atomicAdd(&cursor[ei[E + e]], 1);
        csr[pos] = make_int2(ei[e], e);   // (src, edge id)
    }
}

// ---------------- fused score + online-softmax + aggregation ----------------
// Layer 1: H=8, C=16. One wave/node; lane covers channels (2*lane,2*lane+1) of
// head h=lane>>3. Up to 64 edges' (src,eid) preloaded into lane registers;
// 8-edge chunks with online softmax. Edge-embed term via per-head accumulator
// expanded through We1 in the epilogue.
__global__ __launch_bounds__(256) void fused1_node(
    const unsigned short* __restrict__ P, const float* __restrict__ qWe,
    const float* __restrict__ ea, const float* __restrict__ We1,
    const int2* __restrict__ csr, const int* __restrict__ rowptr,
    unsigned short* __restrict__ h1, int N)
{
    const int lane = threadIdx.x & 63;
    const int node = blockIdx.x * 4 + (threadIdx.x >> 6);
    if (node >= N) return;
    const int beg = rowptr[node];
    const int deg = rowptr[node + 1] - beg;
    const int h = lane >> 3, sub = lane & 7;
    const int c0 = lane * 2;

    float2 skip = bf2(*(const unsigned*)(P + (size_t)node * 512 + 384 + c0));
    unsigned* outp = (unsigned*)(h1 + (size_t)node * 128 + c0);
    if (deg == 0) {
        float s0 = skip.x > 0.f ? skip.x : 0.01f * skip.x;
        float s1 = skip.y > 0.f ? skip.y : 0.01f * skip.y;
        *outp = (unsigned)f2bf(s0) | ((unsigned)f2bf(s1) << 16);
        return;
    }

    float2 q2  = bf2(*(const unsigned*)(P + (size_t)node * 512 + 256 + c0));
    float2 qw2 = *(const float2*)(qWe + (size_t)node * 128 + c0);

    float2 acc = make_float2(0.f, 0.f);
    float2 A2  = make_float2(0.f, 0.f);
    float m = -INFINITY, lden = 0.f;

    int2 se = make_int2(0, 0);
    if (lane < deg) se = csr[beg + lane];

    for (int blk = 0; blk < deg; blk += 64) {
        if (blk) se = (blk + lane < deg) ? csr[beg + blk + lane] : make_int2(0, 0);
        const int bcnt = min(64, deg - blk);
        for (int base = 0; base < bcnt; base += 8) {
            const int cnt = min(8, bcnt - base);
            float2 v2s[8], eas[8];
            float my_s = -INFINITY;
#pragma unroll
            for (int i = 0; i < 8; ++i) {
                if (i < cnt) {  // wave-uniform
                    int sb = __shfl(se.x, base + i, 64);
                    int eb = __shfl(se.y, base + i, 64);
                    uint2 kv = *(const uint2*)(P + (size_t)sb * 512 + lane * 4);  // k pair | v pair
                    float2 k2 = bf2(kv.x);
                    v2s[i]    = bf2(kv.y);
                    float2 e2 = *(const float2*)(ea + (size_t)eb * 16 + sub * 2);
                    eas[i] = e2;
                    float p = q2.x * k2.x + q2.y * k2.y + qw2.x * e2.x + qw2.y * e2.y;
                    p += __shfl_xor(p, 1, 64);
                    p += __shfl_xor(p, 2, 64);
                    p += __shfl_xor(p, 4, 64);   // per-head dot within 8-lane group
                    if (sub == i) my_s = p * 0.25f;  // 1/sqrt(16)
                } else {
                    v2s[i] = make_float2(0.f, 0.f);
                    eas[i] = make_float2(0.f, 0.f);
                }
            }
            float cm = my_s;
            cm = fmaxf(cm, __shfl_xor(cm, 1, 64));
            cm = fmaxf(cm, __shfl_xor(cm, 2, 64));
            cm = fmaxf(cm, __shfl_xor(cm, 4, 64));
            float m_new = fmaxf(m, cm);
            float scale = __expf(m - m_new);       // first chunk: exp(-inf)=0
            float ew = (sub < cnt) ? __expf(my_s - m_new) : 0.f;
            float ds = ew;
            ds += __shfl_xor(ds, 1, 64);
            ds += __shfl_xor(ds, 2, 64);
            ds += __shfl_xor(ds, 4, 64);
            lden = lden * scale + ds;
            acc.x *= scale; acc.y *= scale;
            A2.x  *= scale; A2.y  *= scale;
            m = m_new;
#pragma unroll
            for (int i = 0; i < 8; ++i) {
                float w = __shfl(ew, (h << 3) | i, 64);  // 0 for padded slots
                acc.x += w * v2s[i].x; acc.y += w * v2s[i].y;
                A2.x  += w * eas[i].x; A2.y  += w * eas[i].y;
            }
        }
    }

    float ex = 0.f, ey = 0.f;
#pragma unroll
    for (int k = 0; k < 8; ++k) {
        float ax = __shfl(A2.x, (h << 3) | k, 64);
        float ay = __shfl(A2.y, (h << 3) | k, 64);
        float2 w0 = *(const float2*)(We1 + (2 * k) * 128 + c0);
        float2 w1 = *(const float2*)(We1 + (2 * k + 1) * 128 + c0);
        ex += ax * w0.x + ay * w1.x;
        ey += ax * w0.y + ay * w1.y;
    }
    float inv = 1.f / (lden + 1e-16f);
    float s0 = (acc.x + ex) * inv + skip.x;
    float s1 = (acc.y + ey) * inv + skip.y;
    s0 = s0 > 0.f ? s0 : 0.01f * s0;
    s1 = s1 > 0.f ? s1 : 0.01f * s1;
    *outp = (unsigned)f2bf(s0) | ((unsigned)f2bf(s1) << 16);
}

// Layer 2: H=1, C=128.
__global__ __launch_bounds__(256) void fused2_node(
    const unsigned short* __restrict__ P, const float* __restrict__ qWe,
    const float* __restrict__ ea, const float* __restrict__ We2,
    const int2* __restrict__ csr, const int* __restrict__ rowptr,
    float* __restrict__ out, int N)
{
    const int lane = threadIdx.x & 63;
    const int node = blockIdx.x * 4 + (threadIdx.x >> 6);
    if (node >= N) return;
    const int beg = rowptr[node];
    const int deg = rowptr[node + 1] - beg;
    const int c0 = lane * 2;
    const int k16 = lane & 15;

    float2 skip = bf2(*(const unsigned*)(P + (size_t)node * 512 + 384 + c0));
    float* outp = out + (size_t)node * 128 + c0;
    if (deg == 0) { outp[0] = skip.x; outp[1] = skip.y; return; }

    float2 q2 = bf2(*(const unsigned*)(P + (size_t)node * 512 + 256 + c0));
    float  qw = qWe[(size_t)node * 128 + k16];

    float2 acc = make_float2(0.f, 0.f);
    float  accA = 0.f;   // A[k16], 4 copies across lane quarters
    float m = -INFINITY, lden = 0.f;

    int2 se = make_int2(0, 0);
    if (lane < deg) se = csr[beg + lane];

    for (int blk = 0; blk < deg; blk += 64) {
        if (blk) se = (blk + lane < deg) ? csr[beg + blk + lane] : make_int2(0, 0);
        const int bcnt = min(64, deg - blk);
        for (int base = 0; base < bcnt; base += 8) {
            const int cnt = min(8, bcnt - base);
            float2 v2s[8]; float eas[8];
            float my_s = -INFINITY;
#pragma unroll
            for (int i = 0; i < 8; ++i) {
                if (i < cnt) {  // wave-uniform
                    int sb = __shfl(se.x, base + i, 64);
                    int eb = __shfl(se.y, base + i, 64);
                    uint2 kv = *(const uint2*)(P + (size_t)sb * 512 + lane * 4);
                    float2 k2 = bf2(kv.x);
                    v2s[i]    = bf2(kv.y);
                    float eav = ea[(size_t)eb * 16 + k16];
                    eas[i] = eav;
                    float p = q2.x * k2.x + q2.y * k2.y + 0.25f * qw * eav;  // ea-dot 4x dup
                    p += __shfl_xor(p, 1, 64);
                    p += __shfl_xor(p, 2, 64);
                    p += __shfl_xor(p, 4, 64);
                    p += __shfl_xor(p, 8, 64);
                    p += __shfl_xor(p, 16, 64);
                    p += __shfl_xor(p, 32, 64);
                    if (lane == i) my_s = p * 0.08838834764831845f;  // 1/sqrt(128)
                } else {
                    v2s[i] = make_float2(0.f, 0.f);
                    eas[i] = 0.f;
                }
            }
            float cm = my_s;
#pragma unroll
            for (int mk = 1; mk < 64; mk <<= 1) cm = fmaxf(cm, __shfl_xor(cm, mk, 64));
            float m_new = fmaxf(m, cm);
            float scale = __expf(m - m_new);
            float ew = (lane < cnt) ? __expf(my_s - m_new) : 0.f;
            float ds = ew;
#pragma unroll
            for (int mk = 1; mk < 64; mk <<= 1) ds += __shfl_xor(ds, mk, 64);
            lden = lden * scale + ds;
            acc.x *= scale; acc.y *= scale; accA *= scale;
            m = m_new;
#pragma unroll
            for (int i = 0; i < 8; ++i) {
                float w = __shfl(ew, i, 64);
                acc.x += w * v2s[i].x; acc.y += w * v2s[i].y;
                accA  += w * eas[i];
            }
        }
    }

    float ex = 0.f, ey = 0.f;
#pragma unroll
    for (int k = 0; k < 16; ++k) {
        float ak = __shfl(accA, (lane & 48) | k, 64);
        float2 w2 = *(const float2*)(We2 + k * 128 + c0);
        ex += ak * w2.x;
        ey += ak * w2.y;
    }
    float inv = 1.f / (lden + 1e-16f);
    outp[0] = (acc.x + ex) * inv + skip.x;
    outp[1] = (acc.y + ey) * inv + skip.y;
}

// ---------------- launch ----------------
extern "C" void kernel_launch(void* const* d_in, const int* in_sizes, int n_in,
                              void* d_out, int out_size, void* d_ws, size_t ws_size,
                              hipStream_t stream)
{
    const float* x  = (const float*)d_in[0];
    const int*   ei = (const int*)d_in[1];
    const float* ea = (const float*)d_in[2];
    const float *Wq1 = (const float*)d_in[3],  *bq1 = (const float*)d_in[4];
    const float *Wk1 = (const float*)d_in[5],  *bk1 = (const float*)d_in[6];
    const float *Wv1 = (const float*)d_in[7],  *bv1 = (const float*)d_in[8];
    const float *We1 = (const float*)d_in[9],  *be1 = (const float*)d_in[10];
    const float *Ws1 = (const float*)d_in[11], *bs1 = (const float*)d_in[12];
    const float *Wq2 = (const float*)d_in[13], *bq2 = (const float*)d_in[14];
    const float *Wk2 = (const float*)d_in[15], *bk2 = (const float*)d_in[16];
    const float *Wv2 = (const float*)d_in[17], *bv2 = (const float*)d_in[18];
    const float *We2 = (const float*)d_in[19], *be2 = (const float*)d_in[20];
    const float *Ws2 = (const float*)d_in[21], *bs2 = (const float*)d_in[22];

    const int N = in_sizes[0] / 128;
    const int E = in_sizes[1] / 2;

    char* ws = (char*)d_ws;
    size_t off = 0;
    auto alloc = [&](size_t bytes) -> void* {
        void* p = ws + off;
        off = (off + bytes + 255) & ~(size_t)255;
        return p;
    };
    unsigned short* xb  = (unsigned short*)alloc((size_t)N * 128 * 2);
    unsigned short* P   = (unsigned short*)alloc((size_t)N * 512 * 2);  // bf16 [kv-interleave | q | s]
    unsigned short* h1b = (unsigned short*)alloc((size_t)N * 128 * 2);
    unsigned short* Wt1 = (unsigned short*)alloc((size_t)640 * 128 * 2);
    unsigned short* Wt2 = (unsigned short*)alloc((size_t)640 * 128 * 2);
    float* bias1 = (float*)alloc(640 * 4);
    float* bias2 = (float*)alloc(640 * 4);
    float* qWe   = (float*)alloc((size_t)N * 128 * 4);
    int*  deg    = (int*)alloc((size_t)N * 4);
    int*  rowptr = (int*)alloc((size_t)(N + 1) * 4);
    int*  cursor = (int*)alloc((size_t)N * 4);
    int2* csr    = (int2*)alloc((size_t)E * 8);

    dim3 gemm_grid((N + 63) / 64, 10);
    const int tn = N * 128;
    const int node_blocks = (N + 3) / 4;
    const int prep_blocks = (640 * 128 + 255) / 256;

    // ---- prep (independent of everything else) ----
    convert_x<<<(tn + 255) / 256, 256, 0, stream>>>(x, xb, tn);
    prep_w<<<prep_blocks, 256, 0, stream>>>(Wq1, bq1, Wk1, bk1, Wv1, bv1, be1, Ws1, bs1, We1, 8, Wt1, bias1);
    prep_w<<<prep_blocks, 256, 0, stream>>>(Wq2, bq2, Wk2, bk2, Wv2, bv2, be2, Ws2, bs2, We2, 1, Wt2, bias2);

    // ---- CSR build (shared by both layers) ----
    hipMemsetAsync(deg, 0, (size_t)N * 4, stream);
    degree_kernel<<<(E + 255) / 256, 256, 0, stream>>>(ei, deg, E);
    scan_kernel<<<1, 1024, 0, stream>>>(deg, rowptr, cursor, N);
    scatter_kernel<<<(E + 255) / 256, 256, 0, stream>>>(ei, cursor, csr, E);

    // ---- layer 1 (H=8, C=16, concat) ----
    gemm_bf16<<<gemm_grid, 256, 0, stream>>>(xb, N, Wt1, bias1, P, qWe);
    fused1_node<<<node_blocks, 256, 0, stream>>>(P, qWe, ea, We1, csr, rowptr, h1b, N);

    // ---- layer 2 (H=1, C=128, mean==identity) ----
    gemm_bf16<<<gemm_grid, 256, 0, stream>>>(h1b, N, Wt2, bias2, P, qWe);
    fused2_node<<<node_blocks, 256, 0, stream>>>(P, qWe, ea, We2, csr, rowptr, (float*)d_out, N);
}

// Round 6
// 747.926 us; speedup vs baseline: 12.8204x; 1.0671x over previous
//
#include <hip/hip_runtime.h>
#include <math.h>

typedef __bf16 bf16x8 __attribute__((ext_vector_type(8)));
typedef float f32x4 __attribute__((ext_vector_type(4)));

// ---------------- bf16 helpers ----------------
__device__ __forceinline__ unsigned short f2bf(float f) {
    unsigned u = __float_as_uint(f);
    return (unsigned short)((u + 0x7fffu + ((u >> 16) & 1u)) >> 16);
}
__device__ __forceinline__ float2 bf2(unsigned u) {
    float2 r;
    r.x = __uint_as_float(u << 16);
    r.y = __uint_as_float(u & 0xffff0000u);
    return r;
}

// ---------------- prep: x -> bf16 ----------------
__global__ __launch_bounds__(256) void convert_x(
    const float* __restrict__ x, unsigned short* __restrict__ xb, int total)
{
    int g = blockIdx.x * blockDim.x + threadIdx.x;
    if (g < total) xb[g] = f2bf(x[g]);
}

// ---------------- prep: 640-col transposed bf16 weights + folded bias ----------------
// Output-column order == final P position (kv interleave baked in):
//   p in [0,256): j=p>>2, w=p&3 -> (w<2 ? k' : v') channel 2j+(p&1), i.e.
//     cc = 2*(p>>2)+(p&1), W = (p&2)?Wv:Wk, +be folded into bias.
//   [256,384)=q (Wq,bq); [384,512)=s (Ws,bs);
//   [512,640): qWe fused cols: Wt[c][d] = sum_i Wq[d,h*C+i]*We[kk*128+h*C+i].
__global__ __launch_bounds__(256) void prep_w(
    const float* __restrict__ Wq, const float* __restrict__ bq,
    const float* __restrict__ Wk, const float* __restrict__ bk,
    const float* __restrict__ Wv, const float* __restrict__ bv,
    const float* __restrict__ be,
    const float* __restrict__ Ws, const float* __restrict__ bs,
    const float* __restrict__ We, int H,
    unsigned short* __restrict__ Wt, float* __restrict__ bias)
{
    int g = blockIdx.x * blockDim.x + threadIdx.x;
    const int C = 128 / H;
    if (g < 640) {
        int p = g;
        float b;
        if (p < 256) {
            int cc = 2 * (p >> 2) + (p & 1);
            b = ((p & 2) ? bv[cc] : bk[cc]) + be[cc];
        }
        else if (p < 384) b = bq[p - 256];
        else if (p < 512) b = bs[p - 384];
        else {
            int c2 = p - 512, h = c2 >> 4, kk = c2 & 15;
            b = 0.f;
            if (h < H) for (int i = 0; i < C; ++i) b += bq[h * C + i] * We[kk * 128 + h * C + i];
        }
        bias[p] = b;
    }
    if (g >= 640 * 128) return;
    int p = g >> 7, d = g & 127;
    float w;
    if (p < 256) {
        int cc = 2 * (p >> 2) + (p & 1);
        w = (p & 2) ? Wv[d * 128 + cc] : Wk[d * 128 + cc];
    } else if (p < 384) {
        w = Wq[d * 128 + (p - 256)];
    } else if (p < 512) {
        w = Ws[d * 128 + (p - 384)];
    } else {
        int c2 = p - 512, h = c2 >> 4, kk = c2 & 15;
        w = 0.f;
        if (h < H) for (int i = 0; i < C; ++i) w += Wq[d * 128 + h * C + i] * We[kk * 128 + h * C + i];
    }
    Wt[(size_t)p * 128 + d] = f2bf(w);
}

// ---------------- MFMA bf16 GEMM: [P | qWe] = Xb[m,128] @ Wt + bias ----------------
// C-frag: col=lane&15, row=(lane>>4)*4+reg  [measured: learn_hip m89/m91]
// Epilogue: bf16 tile staged in LDS (XOR-swizzled), coalesced 32 B/lane stores.
__global__ __launch_bounds__(256) void gemm_bf16(
    const unsigned short* __restrict__ Xb, int M,
    const unsigned short* __restrict__ Wt, const float* __restrict__ bias,
    unsigned short* __restrict__ P, float* __restrict__ qWe)
{
    __shared__ unsigned short tile[4][16][64];
    const int wv = threadIdx.x >> 6, lane = threadIdx.x & 63;
    const int row0 = blockIdx.x * 64 + wv * 16;
    const int n0 = blockIdx.y * 64;                 // [0,640)
    const int quad = lane >> 4, l16 = lane & 15;

    f32x4 acc[4] = {};
    int mrow = row0 + l16; if (mrow >= M) mrow = M - 1;  // clamp loads; stores guarded
    const int kb = quad * 8;
#pragma unroll
    for (int kk = 0; kk < 4; ++kk) {
        bf16x8 a = *(const bf16x8*)(Xb + (size_t)mrow * 128 + kk * 32 + kb);
#pragma unroll
        for (int f = 0; f < 4; ++f) {
            bf16x8 b = *(const bf16x8*)(Wt + (size_t)(n0 + f * 16 + l16) * 128 + kk * 32 + kb);
            acc[f] = __builtin_amdgcn_mfma_f32_16x16x32_bf16(a, b, acc[f], 0, 0, 0);
        }
    }
    if (n0 < 512) {
#pragma unroll
        for (int f = 0; f < 4; ++f) {
            float bs = bias[n0 + f * 16 + l16];
#pragma unroll
            for (int r = 0; r < 4; ++r) {
                int row = quad * 4 + r;
                int col = f * 16 + l16;
                tile[wv][row][col ^ ((row & 3) << 4)] = f2bf(acc[f][r] + bs);
            }
        }
        __syncthreads();
        int row = lane >> 2, seg = lane & 3;
        int m = row0 + row;
        if (m < M) {
            const uint4* src = (const uint4*)&tile[wv][row][(seg ^ (row & 3)) << 4];
            uint4* dst = (uint4*)(P + (size_t)m * 512 + n0 + seg * 16);
            dst[0] = src[0];
            dst[1] = src[1];
        }
    } else {
#pragma unroll
        for (int f = 0; f < 4; ++f) {
            int c = n0 + f * 16 + l16;
            float bs = bias[c];
#pragma unroll
            for (int r = 0; r < 4; ++r) {
                int m = row0 + quad * 4 + r;
                if (m < M) qWe[(size_t)m * 128 + (c - 512)] = acc[f][r] + bs;
            }
        }
    }
}

// ---------------- CSR build (int atomics only) ----------------
__global__ __launch_bounds__(256) void degree_kernel(
    const int* __restrict__ ei, int* __restrict__ deg, int E)
{
    int e = blockIdx.x * blockDim.x + threadIdx.x;
    if (e < E) atomicAdd(&deg[ei[E + e]], 1);
}

// single block: thread-serial chunks + one 1024-wide LDS scan
__global__ __launch_bounds__(1024) void scan_kernel(
    const int* __restrict__ deg, int* __restrict__ rowptr,
    int* __restrict__ cursor, int N)
{
    __shared__ int sums[1024];
    const int T = 1024;
    const int C = (N + T - 1) / T;
    const int t = threadIdx.x;
    const int b0 = t * C;
    int s = 0;
    for (int i = 0; i < C; ++i) { int idx = b0 + i; if (idx < N) s += deg[idx]; }
    sums[t] = s;
    __syncthreads();
    for (int ofs = 1; ofs < 1024; ofs <<= 1) {
        int v = (t >= ofs) ? sums[t - ofs] : 0;
        __syncthreads();
        sums[t] += v;
        __syncthreads();
    }
    int run = (t == 0) ? 0 : sums[t - 1];
    if (t == 0) rowptr[0] = 0;
    for (int i = 0; i < C; ++i) {
        int idx = b0 + i;
        if (idx < N) {
            int d = deg[idx];
            cursor[idx] = run;
            run += d;
            rowptr[idx + 1] = run;
        }
    }
}

__global__ __launch_bounds__(256) void scatter_kernel(
    const int* __restrict__ ei, int* __restrict__ cursor,
    int2* __restrict__ csr, int E)
{
    int e = blockIdx.x * blockDim.x + threadIdx.x;
    if (e < E) {
        int pos = atomicAdd(&cursor[ei[E + e]], 1);
        csr[pos] = make_int2(ei[e], e);   // (src, edge id)
    }
}

// ---------------- fused score + online-softmax + aggregation ----------------
// 128-thread blocks (2 nodes/block) for finer completion granularity.
// Layer 1: H=8, C=16. One wave/node; lane covers channels (2*lane,2*lane+1) of
// head h=lane>>3. Up to 64 edges' (src,eid) preloaded; 8-edge chunks with
// online softmax; edge-embed term via per-head accumulator, expanded in epilogue.
__global__ __launch_bounds__(128) void fused1_node(
    const unsigned short* __restrict__ P, const float* __restrict__ qWe,
    const float* __restrict__ ea, const float* __restrict__ We1,
    const int2* __restrict__ csr, const int* __restrict__ rowptr,
    unsigned short* __restrict__ h1, int N)
{
    const int lane = threadIdx.x & 63;
    const int node = blockIdx.x * 2 + (threadIdx.x >> 6);
    if (node >= N) return;
    const int beg = rowptr[node];
    const int deg = rowptr[node + 1] - beg;
    const int h = lane >> 3, sub = lane & 7;
    const int c0 = lane * 2;

    float2 skip = bf2(*(const unsigned*)(P + (size_t)node * 512 + 384 + c0));
    unsigned* outp = (unsigned*)(h1 + (size_t)node * 128 + c0);
    if (deg == 0) {
        float s0 = skip.x > 0.f ? skip.x : 0.01f * skip.x;
        float s1 = skip.y > 0.f ? skip.y : 0.01f * skip.y;
        *outp = (unsigned)f2bf(s0) | ((unsigned)f2bf(s1) << 16);
        return;
    }

    float2 q2  = bf2(*(const unsigned*)(P + (size_t)node * 512 + 256 + c0));
    float2 qw2 = *(const float2*)(qWe + (size_t)node * 128 + c0);

    float2 acc = make_float2(0.f, 0.f);
    float2 A2  = make_float2(0.f, 0.f);
    float m = -INFINITY, lden = 0.f;

    int2 se = make_int2(0, 0);
    if (lane < deg) se = csr[beg + lane];

    for (int blk = 0; blk < deg; blk += 64) {
        if (blk) se = (blk + lane < deg) ? csr[beg + blk + lane] : make_int2(0, 0);
        const int bcnt = min(64, deg - blk);
        for (int base = 0; base < bcnt; base += 8) {
            const int cnt = min(8, bcnt - base);
            float2 v2s[8], eas[8];
            float my_s = -INFINITY;
#pragma unroll
            for (int i = 0; i < 8; ++i) {
                if (i < cnt) {  // wave-uniform
                    int sb = __shfl(se.x, base + i, 64);
                    int eb = __shfl(se.y, base + i, 64);
                    uint2 kv = *(const uint2*)(P + (size_t)sb * 512 + lane * 4);  // k pair | v pair
                    float2 k2 = bf2(kv.x);
                    v2s[i]    = bf2(kv.y);
                    float2 e2 = *(const float2*)(ea + (size_t)eb * 16 + sub * 2);
                    eas[i] = e2;
                    float p = q2.x * k2.x + q2.y * k2.y + qw2.x * e2.x + qw2.y * e2.y;
                    p += __shfl_xor(p, 1, 64);
                    p += __shfl_xor(p, 2, 64);
                    p += __shfl_xor(p, 4, 64);   // per-head dot within 8-lane group
                    if (sub == i) my_s = p * 0.25f;  // 1/sqrt(16)
                } else {
                    v2s[i] = make_float2(0.f, 0.f);
                    eas[i] = make_float2(0.f, 0.f);
                }
            }
            float cm = my_s;
            cm = fmaxf(cm, __shfl_xor(cm, 1, 64));
            cm = fmaxf(cm, __shfl_xor(cm, 2, 64));
            cm = fmaxf(cm, __shfl_xor(cm, 4, 64));
            float m_new = fmaxf(m, cm);
            float scale = __expf(m - m_new);       // first chunk: exp(-inf)=0
            float ew = (sub < cnt) ? __expf(my_s - m_new) : 0.f;
            float ds = ew;
            ds += __shfl_xor(ds, 1, 64);
            ds += __shfl_xor(ds, 2, 64);
            ds += __shfl_xor(ds, 4, 64);
            lden = lden * scale + ds;
            acc.x *= scale; acc.y *= scale;
            A2.x  *= scale; A2.y  *= scale;
            m = m_new;
#pragma unroll
            for (int i = 0; i < 8; ++i) {
                float w = __shfl(ew, (h << 3) | i, 64);  // 0 for padded slots
                acc.x += w * v2s[i].x; acc.y += w * v2s[i].y;
                A2.x  += w * eas[i].x; A2.y  += w * eas[i].y;
            }
        }
    }

    float ex = 0.f, ey = 0.f;
#pragma unroll
    for (int k = 0; k < 8; ++k) {
        float ax = __shfl(A2.x, (h << 3) | k, 64);
        float ay = __shfl(A2.y, (h << 3) | k, 64);
        float2 w0 = *(const float2*)(We1 + (2 * k) * 128 + c0);
        float2 w1 = *(const float2*)(We1 + (2 * k + 1) * 128 + c0);
        ex += ax * w0.x + ay * w1.x;
        ey += ax * w0.y + ay * w1.y;
    }
    float inv = 1.f / (lden + 1e-16f);
    float s0 = (acc.x + ex) * inv + skip.x;
    float s1 = (acc.y + ey) * inv + skip.y;
    s0 = s0 > 0.f ? s0 : 0.01f * s0;
    s1 = s1 > 0.f ? s1 : 0.01f * s1;
    *outp = (unsigned)f2bf(s0) | ((unsigned)f2bf(s1) << 16);
}

// Layer 2: H=1, C=128.
__global__ __launch_bounds__(128) void fused2_node(
    const unsigned short* __restrict__ P, const float* __restrict__ qWe,
    const float* __restrict__ ea, const float* __restrict__ We2,
    const int2* __restrict__ csr, const int* __restrict__ rowptr,
    float* __restrict__ out, int N)
{
    const int lane = threadIdx.x & 63;
    const int node = blockIdx.x * 2 + (threadIdx.x >> 6);
    if (node >= N) return;
    const int beg = rowptr[node];
    const int deg = rowptr[node + 1] - beg;
    const int c0 = lane * 2;
    const int k16 = lane & 15;

    float2 skip = bf2(*(const unsigned*)(P + (size_t)node * 512 + 384 + c0));
    float* outp = out + (size_t)node * 128 + c0;
    if (deg == 0) { outp[0] = skip.x; outp[1] = skip.y; return; }

    float2 q2 = bf2(*(const unsigned*)(P + (size_t)node * 512 + 256 + c0));
    float  qw = qWe[(size_t)node * 128 + k16];

    float2 acc = make_float2(0.f, 0.f);
    float  accA = 0.f;   // A[k16], 4 copies across lane quarters
    float m = -INFINITY, lden = 0.f;

    int2 se = make_int2(0, 0);
    if (lane < deg) se = csr[beg + lane];

    for (int blk = 0; blk < deg; blk += 64) {
        if (blk) se = (blk + lane < deg) ? csr[beg + blk + lane] : make_int2(0, 0);
        const int bcnt = min(64, deg - blk);
        for (int base = 0; base < bcnt; base += 8) {
            const int cnt = min(8, bcnt - base);
            float2 v2s[8]; float eas[8];
            float my_s = -INFINITY;
#pragma unroll
            for (int i = 0; i < 8; ++i) {
                if (i < cnt) {  // wave-uniform
                    int sb = __shfl(se.x, base + i, 64);
                    int eb = __shfl(se.y, base + i, 64);
                    uint2 kv = *(const uint2*)(P + (size_t)sb * 512 + lane * 4);
                    float2 k2 = bf2(kv.x);
                    v2s[i]    = bf2(kv.y);
                    float eav = ea[(size_t)eb * 16 + k16];
                    eas[i] = eav;
                    float p = q2.x * k2.x + q2.y * k2.y + 0.25f * qw * eav;  // ea-dot 4x dup
                    p += __shfl_xor(p, 1, 64);
                    p += __shfl_xor(p, 2, 64);
                    p += __shfl_xor(p, 4, 64);
                    p += __shfl_xor(p, 8, 64);
                    p += __shfl_xor(p, 16, 64);
                    p += __shfl_xor(p, 32, 64);
                    if (lane == i) my_s = p * 0.08838834764831845f;  // 1/sqrt(128)
                } else {
                    v2s[i] = make_float2(0.f, 0.f);
                    eas[i] = 0.f;
                }
            }
            float cm = my_s;
#pragma unroll
            for (int mk = 1; mk < 64; mk <<= 1) cm = fmaxf(cm, __shfl_xor(cm, mk, 64));
            float m_new = fmaxf(m, cm);
            float scale = __expf(m - m_new);
            float ew = (lane < cnt) ? __expf(my_s - m_new) : 0.f;
            float ds = ew;
#pragma unroll
            for (int mk = 1; mk < 64; mk <<= 1) ds += __shfl_xor(ds, mk, 64);
            lden = lden * scale + ds;
            acc.x *= scale; acc.y *= scale; accA *= scale;
            m = m_new;
#pragma unroll
            for (int i = 0; i < 8; ++i) {
                float w = __shfl(ew, i, 64);
                acc.x += w * v2s[i].x; acc.y += w * v2s[i].y;
                accA  += w * eas[i];
            }
        }
    }

    float ex = 0.f, ey = 0.f;
#pragma unroll
    for (int k = 0; k < 16; ++k) {
        float ak = __shfl(accA, (lane & 48) | k, 64);
        float2 w2 = *(const float2*)(We2 + k * 128 + c0);
        ex += ak * w2.x;
        ey += ak * w2.y;
    }
    float inv = 1.f / (lden + 1e-16f);
    outp[0] = (acc.x + ex) * inv + skip.x;
    outp[1] = (acc.y + ey) * inv + skip.y;
}

// ---------------- launch ----------------
extern "C" void kernel_launch(void* const* d_in, const int* in_sizes, int n_in,
                              void* d_out, int out_size, void* d_ws, size_t ws_size,
                              hipStream_t stream)
{
    const float* x  = (const float*)d_in[0];
    const int*   ei = (const int*)d_in[1];
    const float* ea = (const float*)d_in[2];
    const float *Wq1 = (const float*)d_in[3],  *bq1 = (const float*)d_in[4];
    const float *Wk1 = (const float*)d_in[5],  *bk1 = (const float*)d_in[6];
    const float *Wv1 = (const float*)d_in[7],  *bv1 = (const float*)d_in[8];
    const float *We1 = (const float*)d_in[9],  *be1 = (const float*)d_in[10];
    const float *Ws1 = (const float*)d_in[11], *bs1 = (const float*)d_in[12];
    const float *Wq2 = (const float*)d_in[13], *bq2 = (const float*)d_in[14];
    const float *Wk2 = (const float*)d_in[15], *bk2 = (const float*)d_in[16];
    const float *Wv2 = (const float*)d_in[17], *bv2 = (const float*)d_in[18];
    const float *We2 = (const float*)d_in[19], *be2 = (const float*)d_in[20];
    const float *Ws2 = (const float*)d_in[21], *bs2 = (const float*)d_in[22];

    const int N = in_sizes[0] / 128;
    const int E = in_sizes[1] / 2;

    char* ws = (char*)d_ws;
    size_t off = 0;
    auto alloc = [&](size_t bytes) -> void* {
        void* p = ws + off;
        off = (off + bytes + 255) & ~(size_t)255;
        return p;
    };
    unsigned short* xb  = (unsigned short*)alloc((size_t)N * 128 * 2);
    unsigned short* P   = (unsigned short*)alloc((size_t)N * 512 * 2);  // bf16 [kv-interleave | q | s]
    unsigned short* h1b = (unsigned short*)alloc((size_t)N * 128 * 2);
    unsigned short* Wt1 = (unsigned short*)alloc((size_t)640 * 128 * 2);
    unsigned short* Wt2 = (unsigned short*)alloc((size_t)640 * 128 * 2);
    float* bias1 = (float*)alloc(640 * 4);
    float* bias2 = (float*)alloc(640 * 4);
    float* qWe   = (float*)alloc((size_t)N * 128 * 4);
    int*  deg    = (int*)alloc((size_t)N * 4);
    int*  rowptr = (int*)alloc((size_t)(N + 1) * 4);
    int*  cursor = (int*)alloc((size_t)N * 4);
    int2* csr    = (int2*)alloc((size_t)E * 8);

    dim3 gemm_grid1((N + 63) / 64, 10);
    dim3 gemm_grid2((N + 63) / 64, 9);   // layer-2 qWe needs only cols [512,528)
    const int tn = N * 128;
    const int node_blocks = (N + 1) / 2;
    const int prep_blocks = (640 * 128 + 255) / 256;

    // ---- prep (independent of everything else) ----
    convert_x<<<(tn + 255) / 256, 256, 0, stream>>>(x, xb, tn);
    prep_w<<<prep_blocks, 256, 0, stream>>>(Wq1, bq1, Wk1, bk1, Wv1, bv1, be1, Ws1, bs1, We1, 8, Wt1, bias1);
    prep_w<<<prep_blocks, 256, 0, stream>>>(Wq2, bq2, Wk2, bk2, Wv2, bv2, be2, Ws2, bs2, We2, 1, Wt2, bias2);

    // ---- CSR build (shared by both layers) ----
    hipMemsetAsync(deg, 0, (size_t)N * 4, stream);
    degree_kernel<<<(E + 255) / 256, 256, 0, stream>>>(ei, deg, E);
    scan_kernel<<<1, 1024, 0, stream>>>(deg, rowptr, cursor, N);
    scatter_kernel<<<(E + 255) / 256, 256, 0, stream>>>(ei, cursor, csr, E);

    // ---- layer 1 (H=8, C=16, concat) ----
    gemm_bf16<<<gemm_grid1, 256, 0, stream>>>(xb, N, Wt1, bias1, P, qWe);
    fused1_node<<<node_blocks, 128, 0, stream>>>(P, qWe, ea, We1, csr, rowptr, h1b, N);

    // ---- layer 2 (H=1, C=128, mean==identity) ----
    gemm_bf16<<<gemm_grid2, 256, 0, stream>>>(h1b, N, Wt2, bias2, P, qWe);
    fused2_node<<<node_blocks, 128, 0, stream>>>(P, qWe, ea, We2, csr, rowptr, (float*)d_out, N);
}

// Round 7
// 727.528 us; speedup vs baseline: 13.1799x; 1.0280x over previous
//
#include <hip/hip_runtime.h>
#include <math.h>

typedef __bf16 bf16x8 __attribute__((ext_vector_type(8)));
typedef float f32x4 __attribute__((ext_vector_type(4)));

// ---------------- bf16 helpers ----------------
__device__ __forceinline__ unsigned short f2bf(float f) {
    unsigned u = __float_as_uint(f);
    return (unsigned short)((u + 0x7fffu + ((u >> 16) & 1u)) >> 16);
}
__device__ __forceinline__ float2 bf2(unsigned u) {
    float2 r;
    r.x = __uint_as_float(u << 16);
    r.y = __uint_as_float(u & 0xffff0000u);
    return r;
}

// ---------------- prep: x -> bf16 ----------------
__global__ __launch_bounds__(256) void convert_x(
    const float* __restrict__ x, unsigned short* __restrict__ xb, int total)
{
    int g = blockIdx.x * blockDim.x + threadIdx.x;
    if (g < total) xb[g] = f2bf(x[g]);
}

// ---------------- prep: 640-col transposed bf16 weights + folded bias ----------------
// Output-column order == final P position (kv interleave baked in):
//   p in [0,256): cc = 2*(p>>2)+(p&1), W = (p&2)?Wv:Wk, +be folded.
//   [256,384)=q (Wq,bq); [384,512)=s (Ws,bs);
//   [512,640): qWe fused cols: Wt[c][d] = sum_i Wq[d,h*C+i]*We[kk*128+h*C+i].
__global__ __launch_bounds__(256) void prep_w(
    const float* __restrict__ Wq, const float* __restrict__ bq,
    const float* __restrict__ Wk, const float* __restrict__ bk,
    const float* __restrict__ Wv, const float* __restrict__ bv,
    const float* __restrict__ be,
    const float* __restrict__ Ws, const float* __restrict__ bs,
    const float* __restrict__ We, int H,
    unsigned short* __restrict__ Wt, float* __restrict__ bias)
{
    int g = blockIdx.x * blockDim.x + threadIdx.x;
    const int C = 128 / H;
    if (g < 640) {
        int p = g;
        float b;
        if (p < 256) {
            int cc = 2 * (p >> 2) + (p & 1);
            b = ((p & 2) ? bv[cc] : bk[cc]) + be[cc];
        }
        else if (p < 384) b = bq[p - 256];
        else if (p < 512) b = bs[p - 384];
        else {
            int c2 = p - 512, h = c2 >> 4, kk = c2 & 15;
            b = 0.f;
            if (h < H) for (int i = 0; i < C; ++i) b += bq[h * C + i] * We[kk * 128 + h * C + i];
        }
        bias[p] = b;
    }
    if (g >= 640 * 128) return;
    int p = g >> 7, d = g & 127;
    float w;
    if (p < 256) {
        int cc = 2 * (p >> 2) + (p & 1);
        w = (p & 2) ? Wv[d * 128 + cc] : Wk[d * 128 + cc];
    } else if (p < 384) {
        w = Wq[d * 128 + (p - 256)];
    } else if (p < 512) {
        w = Ws[d * 128 + (p - 384)];
    } else {
        int c2 = p - 512, h = c2 >> 4, kk = c2 & 15;
        w = 0.f;
        if (h < H) for (int i = 0; i < C; ++i) w += Wq[d * 128 + h * C + i] * We[kk * 128 + h * C + i];
    }
    Wt[(size_t)p * 128 + d] = f2bf(w);
}

// ---------------- MFMA bf16 GEMM: [P | qWe] = Xb[m,128] @ Wt + bias ----------------
// B tile (64 cols x 128 k, 16 KB) staged in LDS (row stride 136 -> 2-way-only
// bank aliasing, free). C-frag: col=lane&15, row=(lane>>4)*4+reg [m89/m91].
// Epilogue: bf16 tile staged in LDS (XOR-swizzled), coalesced 32 B/lane stores.
__global__ __launch_bounds__(256) void gemm_bf16(
    const unsigned short* __restrict__ Xb, int M,
    const unsigned short* __restrict__ Wt, const float* __restrict__ bias,
    unsigned short* __restrict__ P, float* __restrict__ qWe)
{
    __shared__ unsigned short Bs[64][136];
    __shared__ unsigned short tile[4][16][64];
    const int wv = threadIdx.x >> 6, lane = threadIdx.x & 63;
    const int row0 = blockIdx.x * 64 + wv * 16;
    const int n0 = blockIdx.y * 64;                 // [0,640)
    const int quad = lane >> 4, l16 = lane & 15;

    {   // stage Wt column-tile into LDS: 1024 x uint4, coalesced
        const uint4* gsrc = (const uint4*)(Wt + (size_t)n0 * 128);
#pragma unroll
        for (int u = 0; u < 4; ++u) {
            int v = threadIdx.x + u * 256;
            int col = v >> 4, k8 = v & 15;
            *(uint4*)(&Bs[col][k8 * 8]) = gsrc[v];
        }
    }
    __syncthreads();

    f32x4 acc[4] = {};
    int mrow = row0 + l16; if (mrow >= M) mrow = M - 1;  // clamp loads; stores guarded
    const int kb = quad * 8;
#pragma unroll
    for (int kk = 0; kk < 4; ++kk) {
        bf16x8 a = *(const bf16x8*)(Xb + (size_t)mrow * 128 + kk * 32 + kb);
#pragma unroll
        for (int f = 0; f < 4; ++f) {
            bf16x8 b = *(const bf16x8*)(&Bs[f * 16 + l16][kk * 32 + kb]);
            acc[f] = __builtin_amdgcn_mfma_f32_16x16x32_bf16(a, b, acc[f], 0, 0, 0);
        }
    }
    if (n0 < 512) {
#pragma unroll
        for (int f = 0; f < 4; ++f) {
            float bs = bias[n0 + f * 16 + l16];
#pragma unroll
            for (int r = 0; r < 4; ++r) {
                int row = quad * 4 + r;
                int col = f * 16 + l16;
                tile[wv][row][col ^ ((row & 3) << 4)] = f2bf(acc[f][r] + bs);
            }
        }
        __syncthreads();
        int row = lane >> 2, seg = lane & 3;
        int m = row0 + row;
        if (m < M) {
            const uint4* src = (const uint4*)&tile[wv][row][(seg ^ (row & 3)) << 4];
            uint4* dst = (uint4*)(P + (size_t)m * 512 + n0 + seg * 16);
            dst[0] = src[0];
            dst[1] = src[1];
        }
    } else {
#pragma unroll
        for (int f = 0; f < 4; ++f) {
            int c = n0 + f * 16 + l16;
            float bs = bias[c];
#pragma unroll
            for (int r = 0; r < 4; ++r) {
                int m = row0 + quad * 4 + r;
                if (m < M) qWe[(size_t)m * 128 + (c - 512)] = acc[f][r] + bs;
            }
        }
    }
}

// ---------------- CSR build (int atomics only) ----------------
__global__ __launch_bounds__(256) void degree_kernel(
    const int* __restrict__ ei, int* __restrict__ deg, int E)
{
    int e = blockIdx.x * blockDim.x + threadIdx.x;
    if (e < E) atomicAdd(&deg[ei[E + e]], 1);
}

// single block: thread-serial chunks + one 1024-wide LDS scan
__global__ __launch_bounds__(1024) void scan_kernel(
    const int* __restrict__ deg, int* __restrict__ rowptr,
    int* __restrict__ cursor, int N)
{
    __shared__ int sums[1024];
    const int T = 1024;
    const int C = (N + T - 1) / T;
    const int t = threadIdx.x;
    const int b0 = t * C;
    int s = 0;
    for (int i = 0; i < C; ++i) { int idx = b0 + i; if (idx < N) s += deg[idx]; }
    sums[t] = s;
    __syncthreads();
    for (int ofs = 1; ofs < 1024; ofs <<= 1) {
        int v = (t >= ofs) ? sums[t - ofs] : 0;
        __syncthreads();
        sums[t] += v;
        __syncthreads();
    }
    int run = (t == 0) ? 0 : sums[t - 1];
    if (t == 0) rowptr[0] = 0;
    for (int i = 0; i < C; ++i) {
        int idx = b0 + i;
        if (idx < N) {
            int d = deg[idx];
            cursor[idx] = run;
            run += d;
            rowptr[idx + 1] = run;
        }
    }
}

__global__ __launch_bounds__(256) void scatter_kernel(
    const int* __restrict__ ei, int* __restrict__ cursor,
    int2* __restrict__ csr, int E)
{
    int e = blockIdx.x * blockDim.x + threadIdx.x;
    if (e < E) {
        int pos = atomicAdd(&cursor[ei[E + e]], 1);
        csr[pos] = make_int2(ei[e], e);   // (src, edge id)
    }
}

// ---------------- fused score + online-softmax + aggregation ----------------
// 128-thread blocks (2 nodes/block). Chunks of 16 edges, BRANCHLESS gather
// phase (all 16 row-gathers in flight), then score/softmax/accumulate.
// Layer 1: H=8,C=16; lane covers channels (2*lane,2*lane+1) of head lane>>3;
// two score slots per lane (sub-lanes 0..7 hold edges base+i and base+8+i).
__global__ __launch_bounds__(128) void fused1_node(
    const unsigned short* __restrict__ P, const float* __restrict__ qWe,
    const float* __restrict__ ea, const float* __restrict__ We1,
    const int2* __restrict__ csr, const int* __restrict__ rowptr,
    unsigned short* __restrict__ h1, int N)
{
    const int lane = threadIdx.x & 63;
    const int node = blockIdx.x * 2 + (threadIdx.x >> 6);
    if (node >= N) return;
    const int beg = rowptr[node];
    const int deg = rowptr[node + 1] - beg;
    const int h = lane >> 3, sub = lane & 7;
    const int c0 = lane * 2;

    float2 skip = bf2(*(const unsigned*)(P + (size_t)node * 512 + 384 + c0));
    unsigned* outp = (unsigned*)(h1 + (size_t)node * 128 + c0);
    if (deg == 0) {
        float s0 = skip.x > 0.f ? skip.x : 0.01f * skip.x;
        float s1 = skip.y > 0.f ? skip.y : 0.01f * skip.y;
        *outp = (unsigned)f2bf(s0) | ((unsigned)f2bf(s1) << 16);
        return;
    }

    float2 q2  = bf2(*(const unsigned*)(P + (size_t)node * 512 + 256 + c0));
    float2 qw2 = *(const float2*)(qWe + (size_t)node * 128 + c0);

    float2 acc = make_float2(0.f, 0.f);
    float2 A2  = make_float2(0.f, 0.f);
    float m = -INFINITY, lden = 0.f;

    int2 se = make_int2(0, 0);
    if (lane < deg) se = csr[beg + lane];

    for (int blk = 0; blk < deg; blk += 64) {
        if (blk) se = (blk + lane < deg) ? csr[beg + blk + lane] : make_int2(0, 0);
        const int bcnt = min(64, deg - blk);
        for (int base = 0; base < bcnt; base += 16) {
            const int cnt = min(16, bcnt - base);
            uint2 kv[16]; float2 ea2[16];
            // ---- gather phase: branchless, 16 loads in flight ----
#pragma unroll
            for (int i = 0; i < 16; ++i) {
                int j = base + ((i < cnt) ? i : cnt - 1);
                int sb = __shfl(se.x, j, 64);
                int eb = __shfl(se.y, j, 64);
                kv[i]  = *(const uint2*)(P + (size_t)sb * 512 + lane * 4);  // k pair | v pair
                ea2[i] = *(const float2*)(ea + (size_t)eb * 16 + sub * 2);
            }
            // ---- score phase ----
            float my_s0 = -INFINITY, my_s1 = -INFINITY;
#pragma unroll
            for (int i = 0; i < 16; ++i) {
                float2 k2 = bf2(kv[i].x);
                float p = q2.x * k2.x + q2.y * k2.y + qw2.x * ea2[i].x + qw2.y * ea2[i].y;
                p += __shfl_xor(p, 1, 64);
                p += __shfl_xor(p, 2, 64);
                p += __shfl_xor(p, 4, 64);   // per-head dot within 8-lane group
                if (sub == (i & 7)) {
                    float v = (i < cnt) ? p * 0.25f : -INFINITY;  // 1/sqrt(16)
                    if (i < 8) my_s0 = v; else my_s1 = v;
                }
            }
            // ---- online softmax update ----
            float cm = fmaxf(my_s0, my_s1);
            cm = fmaxf(cm, __shfl_xor(cm, 1, 64));
            cm = fmaxf(cm, __shfl_xor(cm, 2, 64));
            cm = fmaxf(cm, __shfl_xor(cm, 4, 64));
            float m_new = fmaxf(m, cm);
            float scale = __expf(m - m_new);       // first chunk: exp(-inf)=0
            float ew0 = __expf(my_s0 - m_new);     // padded: exp(-inf)=0
            float ew1 = __expf(my_s1 - m_new);
            float ds = ew0 + ew1;
            ds += __shfl_xor(ds, 1, 64);
            ds += __shfl_xor(ds, 2, 64);
            ds += __shfl_xor(ds, 4, 64);
            lden = lden * scale + ds;
            acc.x *= scale; acc.y *= scale;
            A2.x  *= scale; A2.y  *= scale;
            m = m_new;
            // ---- accumulate phase ----
#pragma unroll
            for (int i = 0; i < 16; ++i) {
                float ew_i = (i < 8) ? ew0 : ew1;  // uniform select
                float w = __shfl(ew_i, (h << 3) | (i & 7), 64);
                float2 v2 = bf2(kv[i].y);
                acc.x += w * v2.x; acc.y += w * v2.y;
                A2.x  += w * ea2[i].x; A2.y  += w * ea2[i].y;
            }
        }
    }

    float ex = 0.f, ey = 0.f;
#pragma unroll
    for (int k = 0; k < 8; ++k) {
        float ax = __shfl(A2.x, (h << 3) | k, 64);
        float ay = __shfl(A2.y, (h << 3) | k, 64);
        float2 w0 = *(const float2*)(We1 + (2 * k) * 128 + c0);
        float2 w1 = *(const float2*)(We1 + (2 * k + 1) * 128 + c0);
        ex += ax * w0.x + ay * w1.x;
        ey += ax * w0.y + ay * w1.y;
    }
    float inv = 1.f / (lden + 1e-16f);
    float s0 = (acc.x + ex) * inv + skip.x;
    float s1 = (acc.y + ey) * inv + skip.y;
    s0 = s0 > 0.f ? s0 : 0.01f * s0;
    s1 = s1 > 0.f ? s1 : 0.01f * s1;
    *outp = (unsigned)f2bf(s0) | ((unsigned)f2bf(s1) << 16);
}

// Layer 2: H=1, C=128. Lanes 0..15 hold the chunk's 16 edge scores.
__global__ __launch_bounds__(128) void fused2_node(
    const unsigned short* __restrict__ P, const float* __restrict__ qWe,
    const float* __restrict__ ea, const float* __restrict__ We2,
    const int2* __restrict__ csr, const int* __restrict__ rowptr,
    float* __restrict__ out, int N)
{
    const int lane = threadIdx.x & 63;
    const int node = blockIdx.x * 2 + (threadIdx.x >> 6);
    if (node >= N) return;
    const int beg = rowptr[node];
    const int deg = rowptr[node + 1] - beg;
    const int c0 = lane * 2;
    const int k16 = lane & 15;

    float2 skip = bf2(*(const unsigned*)(P + (size_t)node * 512 + 384 + c0));
    float* outp = out + (size_t)node * 128 + c0;
    if (deg == 0) { outp[0] = skip.x; outp[1] = skip.y; return; }

    float2 q2 = bf2(*(const unsigned*)(P + (size_t)node * 512 + 256 + c0));
    float  qw = qWe[(size_t)node * 128 + k16];

    float2 acc = make_float2(0.f, 0.f);
    float  accA = 0.f;   // A[k16], 4 copies across lane quarters
    float m = -INFINITY, lden = 0.f;

    int2 se = make_int2(0, 0);
    if (lane < deg) se = csr[beg + lane];

    for (int blk = 0; blk < deg; blk += 64) {
        if (blk) se = (blk + lane < deg) ? csr[beg + blk + lane] : make_int2(0, 0);
        const int bcnt = min(64, deg - blk);
        for (int base = 0; base < bcnt; base += 16) {
            const int cnt = min(16, bcnt - base);
            uint2 kv[16]; float eav[16];
            // ---- gather phase: branchless, 16 loads in flight ----
#pragma unroll
            for (int i = 0; i < 16; ++i) {
                int j = base + ((i < cnt) ? i : cnt - 1);
                int sb = __shfl(se.x, j, 64);
                int eb = __shfl(se.y, j, 64);
                kv[i]  = *(const uint2*)(P + (size_t)sb * 512 + lane * 4);
                eav[i] = ea[(size_t)eb * 16 + k16];
            }
            // ---- score phase ----
            float my_s = -INFINITY;
#pragma unroll
            for (int i = 0; i < 16; ++i) {
                float2 k2 = bf2(kv[i].x);
                float p = q2.x * k2.x + q2.y * k2.y + 0.25f * qw * eav[i];  // ea-dot 4x dup
                p += __shfl_xor(p, 1, 64);
                p += __shfl_xor(p, 2, 64);
                p += __shfl_xor(p, 4, 64);
                p += __shfl_xor(p, 8, 64);
                p += __shfl_xor(p, 16, 64);
                p += __shfl_xor(p, 32, 64);
                if (lane == i) my_s = (i < cnt) ? p * 0.08838834764831845f : -INFINITY;
            }
            // ---- online softmax update ----
            float cm = my_s;
#pragma unroll
            for (int mk = 1; mk < 64; mk <<= 1) cm = fmaxf(cm, __shfl_xor(cm, mk, 64));
            float m_new = fmaxf(m, cm);
            float scale = __expf(m - m_new);
            float ew = __expf(my_s - m_new);   // padded: 0
            float ds = ew;
#pragma unroll
            for (int mk = 1; mk < 64; mk <<= 1) ds += __shfl_xor(ds, mk, 64);
            lden = lden * scale + ds;
            acc.x *= scale; acc.y *= scale; accA *= scale;
            m = m_new;
            // ---- accumulate phase ----
#pragma unroll
            for (int i = 0; i < 16; ++i) {
                float w = __shfl(ew, i, 64);
                float2 v2 = bf2(kv[i].y);
                acc.x += w * v2.x; acc.y += w * v2.y;
                accA  += w * eav[i];
            }
        }
    }

    float ex = 0.f, ey = 0.f;
#pragma unroll
    for (int k = 0; k < 16; ++k) {
        float ak = __shfl(accA, (lane & 48) | k, 64);
        float2 w2 = *(const float2*)(We2 + k * 128 + c0);
        ex += ak * w2.x;
        ey += ak * w2.y;
    }
    float inv = 1.f / (lden + 1e-16f);
    outp[0] = (acc.x + ex) * inv + skip.x;
    outp[1] = (acc.y + ey) * inv + skip.y;
}

// ---------------- launch ----------------
extern "C" void kernel_launch(void* const* d_in, const int* in_sizes, int n_in,
                              void* d_out, int out_size, void* d_ws, size_t ws_size,
                              hipStream_t stream)
{
    const float* x  = (const float*)d_in[0];
    const int*   ei = (const int*)d_in[1];
    const float* ea = (const float*)d_in[2];
    const float *Wq1 = (const float*)d_in[3],  *bq1 = (const float*)d_in[4];
    const float *Wk1 = (const float*)d_in[5],  *bk1 = (const float*)d_in[6];
    const float *Wv1 = (const float*)d_in[7],  *bv1 = (const float*)d_in[8];
    const float *We1 = (const float*)d_in[9],  *be1 = (const float*)d_in[10];
    const float *Ws1 = (const float*)d_in[11], *bs1 = (const float*)d_in[12];
    const float *Wq2 = (const float*)d_in[13], *bq2 = (const float*)d_in[14];
    const float *Wk2 = (const float*)d_in[15], *bk2 = (const float*)d_in[16];
    const float *Wv2 = (const float*)d_in[17], *bv2 = (const float*)d_in[18];
    const float *We2 = (const float*)d_in[19], *be2 = (const float*)d_in[20];
    const float *Ws2 = (const float*)d_in[21], *bs2 = (const float*)d_in[22];

    const int N = in_sizes[0] / 128;
    const int E = in_sizes[1] / 2;

    char* ws = (char*)d_ws;
    size_t off = 0;
    auto alloc = [&](size_t bytes) -> void* {
        void* p = ws + off;
        off = (off + bytes + 255) & ~(size_t)255;
        return p;
    };
    unsigned short* xb  = (unsigned short*)alloc((size_t)N * 128 * 2);
    unsigned short* P   = (unsigned short*)alloc((size_t)N * 512 * 2);  // bf16 [kv-interleave | q | s]
    unsigned short* h1b = (unsigned short*)alloc((size_t)N * 128 * 2);
    unsigned short* Wt1 = (unsigned short*)alloc((size_t)640 * 128 * 2);
    unsigned short* Wt2 = (unsigned short*)alloc((size_t)640 * 128 * 2);
    float* bias1 = (float*)alloc(640 * 4);
    float* bias2 = (float*)alloc(640 * 4);
    float* qWe   = (float*)alloc((size_t)N * 128 * 4);
    int*  deg    = (int*)alloc((size_t)N * 4);
    int*  rowptr = (int*)alloc((size_t)(N + 1) * 4);
    int*  cursor = (int*)alloc((size_t)N * 4);
    int2* csr    = (int2*)alloc((size_t)E * 8);

    dim3 gemm_grid1((N + 63) / 64, 10);
    dim3 gemm_grid2((N + 63) / 64, 9);   // layer-2 qWe needs only cols [512,528)
    const int tn = N * 128;
    const int node_blocks = (N + 1) / 2;
    const int prep_blocks = (640 * 128 + 255) / 256;

    // ---- prep (independent of everything else) ----
    convert_x<<<(tn + 255) / 256, 256, 0, stream>>>(x, xb, tn);
    prep_w<<<prep_blocks, 256, 0, stream>>>(Wq1, bq1, Wk1, bk1, Wv1, bv1, be1, Ws1, bs1, We1, 8, Wt1, bias1);
    prep_w<<<prep_blocks, 256, 0, stream>>>(Wq2, bq2, Wk2, bk2, Wv2, bv2, be2, Ws2, bs2, We2, 1, Wt2, bias2);

    // ---- CSR build (shared by both layers) ----
    hipMemsetAsync(deg, 0, (size_t)N * 4, stream);
    degree_kernel<<<(E + 255) / 256, 256, 0, stream>>>(ei, deg, E);
    scan_kernel<<<1, 1024, 0, stream>>>(deg, rowptr, cursor, N);
    scatter_kernel<<<(E + 255) / 256, 256, 0, stream>>>(ei, cursor, csr, E);

    // ---- layer 1 (H=8, C=16, concat) ----
    gemm_bf16<<<gemm_grid1, 256, 0, stream>>>(xb, N, Wt1, bias1, P, qWe);
    fused1_node<<<node_blocks, 128, 0, stream>>>(P, qWe, ea, We1, csr, rowptr, h1b, N);

    // ---- layer 2 (H=1, C=128, mean==identity) ----
    gemm_bf16<<<gemm_grid2, 256, 0, stream>>>(h1b, N, Wt2, bias2, P, qWe);
    fused2_node<<<node_blocks, 128, 0, stream>>>(P, qWe, ea, We2, csr, rowptr, (float*)d_out, N);
}

// Round 8
// 670.258 us; speedup vs baseline: 14.3060x; 1.0854x over previous
//
#include <hip/hip_runtime.h>
#include <math.h>

typedef __bf16 bf16x8 __attribute__((ext_vector_type(8)));
typedef float f32x4 __attribute__((ext_vector_type(4)));

// ---------------- bf16 helpers ----------------
__device__ __forceinline__ unsigned short f2bf(float f) {
    unsigned u = __float_as_uint(f);
    return (unsigned short)((u + 0x7fffu + ((u >> 16) & 1u)) >> 16);
}
__device__ __forceinline__ float2 bf2(unsigned u) {
    float2 r;
    r.x = __uint_as_float(u << 16);
    r.y = __uint_as_float(u & 0xffff0000u);
    return r;
}

// ---------------- prep: x -> bf16 ----------------
__global__ __launch_bounds__(256) void convert_x(
    const float* __restrict__ x, unsigned short* __restrict__ xb, int total)
{
    int g = blockIdx.x * blockDim.x + threadIdx.x;
    if (g < total) xb[g] = f2bf(x[g]);
}

// ---------------- prep: 640-col transposed bf16 weights + folded bias ----------------
// Output-column order == final P position (kv interleave baked in):
//   p in [0,256): cc = 2*(p>>2)+(p&1), W = (p&2)?Wv:Wk, +be folded.
//   [256,384)=q (Wq,bq); [384,512)=s (Ws,bs);
//   [512,640): qWe fused cols: Wt[c][d] = sum_i Wq[d,h*C+i]*We[kk*128+h*C+i].
__global__ __launch_bounds__(256) void prep_w(
    const float* __restrict__ Wq, const float* __restrict__ bq,
    const float* __restrict__ Wk, const float* __restrict__ bk,
    const float* __restrict__ Wv, const float* __restrict__ bv,
    const float* __restrict__ be,
    const float* __restrict__ Ws, const float* __restrict__ bs,
    const float* __restrict__ We, int H,
    unsigned short* __restrict__ Wt, float* __restrict__ bias)
{
    int g = blockIdx.x * blockDim.x + threadIdx.x;
    const int C = 128 / H;
    if (g < 640) {
        int p = g;
        float b;
        if (p < 256) {
            int cc = 2 * (p >> 2) + (p & 1);
            b = ((p & 2) ? bv[cc] : bk[cc]) + be[cc];
        }
        else if (p < 384) b = bq[p - 256];
        else if (p < 512) b = bs[p - 384];
        else {
            int c2 = p - 512, h = c2 >> 4, kk = c2 & 15;
            b = 0.f;
            if (h < H) for (int i = 0; i < C; ++i) b += bq[h * C + i] * We[kk * 128 + h * C + i];
        }
        bias[p] = b;
    }
    if (g >= 640 * 128) return;
    int p = g >> 7, d = g & 127;
    float w;
    if (p < 256) {
        int cc = 2 * (p >> 2) + (p & 1);
        w = (p & 2) ? Wv[d * 128 + cc] : Wk[d * 128 + cc];
    } else if (p < 384) {
        w = Wq[d * 128 + (p - 256)];
    } else if (p < 512) {
        w = Ws[d * 128 + (p - 384)];
    } else {
        int c2 = p - 512, h = c2 >> 4, kk = c2 & 15;
        w = 0.f;
        if (h < H) for (int i = 0; i < C; ++i) w += Wq[d * 128 + h * C + i] * We[kk * 128 + h * C + i];
    }
    Wt[(size_t)p * 128 + d] = f2bf(w);
}

// ---------------- MFMA bf16 GEMM: [P | qWe] = Xb[m,128] @ Wt + bias ----------------
// B tile (64 cols x 128 k, 16 KB) staged in LDS. C-frag: col=lane&15,
// row=(lane>>4)*4+reg [m89/m91]. Epilogue via LDS for coalesced stores.
__global__ __launch_bounds__(256) void gemm_bf16(
    const unsigned short* __restrict__ Xb, int M,
    const unsigned short* __restrict__ Wt, const float* __restrict__ bias,
    unsigned short* __restrict__ P, float* __restrict__ qWe)
{
    __shared__ unsigned short Bs[64][136];
    __shared__ unsigned short tile[4][16][64];
    const int wv = threadIdx.x >> 6, lane = threadIdx.x & 63;
    const int row0 = blockIdx.x * 64 + wv * 16;
    const int n0 = blockIdx.y * 64;                 // [0,640)
    const int quad = lane >> 4, l16 = lane & 15;

    {   // stage Wt column-tile into LDS: 1024 x uint4, coalesced
        const uint4* gsrc = (const uint4*)(Wt + (size_t)n0 * 128);
#pragma unroll
        for (int u = 0; u < 4; ++u) {
            int v = threadIdx.x + u * 256;
            int col = v >> 4, k8 = v & 15;
            *(uint4*)(&Bs[col][k8 * 8]) = gsrc[v];
        }
    }
    __syncthreads();

    f32x4 acc[4] = {};
    int mrow = row0 + l16; if (mrow >= M) mrow = M - 1;  // clamp loads; stores guarded
    const int kb = quad * 8;
#pragma unroll
    for (int kk = 0; kk < 4; ++kk) {
        bf16x8 a = *(const bf16x8*)(Xb + (size_t)mrow * 128 + kk * 32 + kb);
#pragma unroll
        for (int f = 0; f < 4; ++f) {
            bf16x8 b = *(const bf16x8*)(&Bs[f * 16 + l16][kk * 32 + kb]);
            acc[f] = __builtin_amdgcn_mfma_f32_16x16x32_bf16(a, b, acc[f], 0, 0, 0);
        }
    }
    if (n0 < 512) {
#pragma unroll
        for (int f = 0; f < 4; ++f) {
            float bs = bias[n0 + f * 16 + l16];
#pragma unroll
            for (int r = 0; r < 4; ++r) {
                int row = quad * 4 + r;
                int col = f * 16 + l16;
                tile[wv][row][col ^ ((row & 3) << 4)] = f2bf(acc[f][r] + bs);
            }
        }
        __syncthreads();
        int row = lane >> 2, seg = lane & 3;
        int m = row0 + row;
        if (m < M) {
            const uint4* src = (const uint4*)&tile[wv][row][(seg ^ (row & 3)) << 4];
            uint4* dst = (uint4*)(P + (size_t)m * 512 + n0 + seg * 16);
            dst[0] = src[0];
            dst[1] = src[1];
        }
    } else {
#pragma unroll
        for (int f = 0; f < 4; ++f) {
            int c = n0 + f * 16 + l16;
            float bs = bias[c];
#pragma unroll
            for (int r = 0; r < 4; ++r) {
                int m = row0 + quad * 4 + r;
                if (m < M) qWe[(size_t)m * 128 + (c - 512)] = acc[f][r] + bs;
            }
        }
    }
}

// ---------------- CSR build (int atomics only) ----------------
__global__ __launch_bounds__(256) void degree_kernel(
    const int* __restrict__ ei, int* __restrict__ deg, int E)
{
    int e = blockIdx.x * blockDim.x + threadIdx.x;
    if (e < E) atomicAdd(&deg[ei[E + e]], 1);
}

__global__ __launch_bounds__(1024) void scan_kernel(
    const int* __restrict__ deg, int* __restrict__ rowptr,
    int* __restrict__ cursor, int N)
{
    __shared__ int sums[1024];
    const int T = 1024;
    const int C = (N + T - 1) / T;
    const int t = threadIdx.x;
    const int b0 = t * C;
    int s = 0;
    for (int i = 0; i < C; ++i) { int idx = b0 + i; if (idx < N) s += deg[idx]; }
    sums[t] = s;
    __syncthreads();
    for (int ofs = 1; ofs < 1024; ofs <<= 1) {
        int v = (t >= ofs) ? sums[t - ofs] : 0;
        __syncthreads();
        sums[t] += v;
        __syncthreads();
    }
    int run = (t == 0) ? 0 : sums[t - 1];
    if (t == 0) rowptr[0] = 0;
    for (int i = 0; i < C; ++i) {
        int idx = b0 + i;
        if (idx < N) {
            int d = deg[idx];
            cursor[idx] = run;
            run += d;
            rowptr[idx + 1] = run;
        }
    }
}

__global__ __launch_bounds__(256) void scatter_kernel(
    const int* __restrict__ ei, int* __restrict__ cursor,
    int2* __restrict__ csr, int E)
{
    int e = blockIdx.x * blockDim.x + threadIdx.x;
    if (e < E) {
        int pos = atomicAdd(&cursor[ei[E + e]], 1);
        csr[pos] = make_int2(ei[e], e);   // (src, edge id)
    }
}

// ---------------- fused score + online-softmax + aggregation ----------------
// NEW STRUCTURE: 32 lanes per node slice, TWO edges per wave instruction.
// Lane covers 4 channels (uint4 = k2|v2|k2|v2); half = lane>>5 handles edge
// parity. 16-edge chunks: loads-only gather phase (8 kv + 8 ea in flight),
// then score/softmax/accumulate. Halves combined via xor-32 in the epilogue.
// Layer 1: H=8, C=16 -> head h = (lane&31)>>2, 4-lane head groups, 2 score
// slots/lane (owner sub4 == i&3, slot = i>>2).
__global__ __launch_bounds__(128, 4) void fused1_node(
    const unsigned short* __restrict__ P, const float* __restrict__ qWe,
    const float* __restrict__ ea, const float* __restrict__ We1,
    const int2* __restrict__ csr, const int* __restrict__ rowptr,
    unsigned short* __restrict__ h1, int N)
{
    const int lane = threadIdx.x & 63;
    const int node = blockIdx.x * 2 + (threadIdx.x >> 6);
    if (node >= N) return;
    const int l32 = lane & 31, half = lane >> 5;
    const int sub4 = l32 & 3;
    const int c0 = l32 * 4;
    const int hsrc = (lane & 32) | (l32 & 28);   // my half's slot-owner base for my head

    const int beg = rowptr[node];
    const int deg = rowptr[node + 1] - beg;

    uint2 su = *(const uint2*)(P + (size_t)node * 512 + 384 + c0);
    float2 ska = bf2(su.x), skb = bf2(su.y);
    if (deg == 0) {
        if (half == 0) {
            float o0 = ska.x > 0.f ? ska.x : 0.01f * ska.x;
            float o1 = ska.y > 0.f ? ska.y : 0.01f * ska.y;
            float o2 = skb.x > 0.f ? skb.x : 0.01f * skb.x;
            float o3 = skb.y > 0.f ? skb.y : 0.01f * skb.y;
            uint2 pk;
            pk.x = (unsigned)f2bf(o0) | ((unsigned)f2bf(o1) << 16);
            pk.y = (unsigned)f2bf(o2) | ((unsigned)f2bf(o3) << 16);
            *(uint2*)(h1 + (size_t)node * 128 + c0) = pk;
        }
        return;
    }

    uint2 qu = *(const uint2*)(P + (size_t)node * 512 + 256 + c0);
    float2 qa = bf2(qu.x), qb = bf2(qu.y);
    float4 qw4 = *(const float4*)(qWe + (size_t)node * 128 + c0);

    float4 acc = make_float4(0.f, 0.f, 0.f, 0.f);
    float4 A2  = make_float4(0.f, 0.f, 0.f, 0.f);
    float m = -INFINITY, lden = 0.f;

    int2 se = make_int2(0, 0);
    if (lane < deg) se = csr[beg + lane];

    for (int blk = 0; blk < deg; blk += 64) {
        if (blk) se = (blk + lane < deg) ? csr[beg + blk + lane] : make_int2(0, 0);
        const int bcnt = min(64, deg - blk);
        for (int cb = 0; cb < bcnt; cb += 16) {
            const int lim = min(16, bcnt - cb);
            uint4 kv[8]; float4 ea4[8];
            // ---- gather phase: loads only, up to 16 in flight ----
#pragma unroll
            for (int i = 0; i < 8; ++i) {
                if (2 * i < lim) {   // wave-uniform
                    int jj = cb + 2 * i + half;
                    int jc = min(jj, bcnt - 1);
                    int sb = __shfl(se.x, jc, 64);
                    int eb = __shfl(se.y, jc, 64);
                    kv[i]  = *(const uint4*)(P + (size_t)sb * 512 + l32 * 8);
                    ea4[i] = *(const float4*)(ea + (size_t)eb * 16 + sub4 * 4);
                }
            }
            // ---- score phase ----
            float s0 = -INFINITY, s1 = -INFINITY;
#pragma unroll
            for (int i = 0; i < 8; ++i) {
                if (2 * i < lim) {
                    float2 ka = bf2(kv[i].x), kb = bf2(kv[i].z);
                    float p = qa.x * ka.x + qa.y * ka.y + qb.x * kb.x + qb.y * kb.y
                            + qw4.x * ea4[i].x + qw4.y * ea4[i].y
                            + qw4.z * ea4[i].z + qw4.w * ea4[i].w;
                    p += __shfl_xor(p, 1, 64);
                    p += __shfl_xor(p, 2, 64);    // 4-lane head group
                    bool valid = (cb + 2 * i + half) < bcnt;
                    float pv = valid ? p * 0.25f : -INFINITY;   // 1/sqrt(16)
                    if (sub4 == (i & 3)) { if (i < 4) s0 = pv; else s1 = pv; }
                }
            }
            // ---- online softmax update (per head, across halves) ----
            float cm = fmaxf(s0, s1);
            cm = fmaxf(cm, __shfl_xor(cm, 1, 64));
            cm = fmaxf(cm, __shfl_xor(cm, 2, 64));
            cm = fmaxf(cm, __shfl_xor(cm, 32, 64));
            float m_new = fmaxf(m, cm);
            float scale = __expf(m - m_new);      // first chunk: exp(-inf)=0
            float e0 = __expf(s0 - m_new);        // unassigned slots: 0
            float e1 = __expf(s1 - m_new);
            float ds = e0 + e1;
            ds += __shfl_xor(ds, 1, 64);
            ds += __shfl_xor(ds, 2, 64);
            ds += __shfl_xor(ds, 32, 64);
            lden = lden * scale + ds;
            acc.x *= scale; acc.y *= scale; acc.z *= scale; acc.w *= scale;
            A2.x  *= scale; A2.y  *= scale; A2.z  *= scale; A2.w  *= scale;
            m = m_new;
            // ---- accumulate phase (my half's edges only) ----
#pragma unroll
            for (int i = 0; i < 8; ++i) {
                if (2 * i < lim) {
                    float w = __shfl((i < 4) ? e0 : e1, hsrc | (i & 3), 64);
                    float2 va = bf2(kv[i].y), vb = bf2(kv[i].w);
                    acc.x += w * va.x; acc.y += w * va.y;
                    acc.z += w * vb.x; acc.w += w * vb.y;
                    A2.x += w * ea4[i].x; A2.y += w * ea4[i].y;
                    A2.z += w * ea4[i].z; A2.w += w * ea4[i].w;
                }
            }
        }
    }
    // combine halves
    acc.x += __shfl_xor(acc.x, 32, 64); acc.y += __shfl_xor(acc.y, 32, 64);
    acc.z += __shfl_xor(acc.z, 32, 64); acc.w += __shfl_xor(acc.w, 32, 64);
    A2.x  += __shfl_xor(A2.x, 32, 64);  A2.y  += __shfl_xor(A2.y, 32, 64);
    A2.z  += __shfl_xor(A2.z, 32, 64);  A2.w  += __shfl_xor(A2.w, 32, 64);

    // expand A_h through We1
    float ex0 = 0.f, ex1 = 0.f, ex2 = 0.f, ex3 = 0.f;
#pragma unroll
    for (int k = 0; k < 16; ++k) {
        float comp = (k & 3) == 0 ? A2.x : (k & 3) == 1 ? A2.y : (k & 3) == 2 ? A2.z : A2.w;
        float ak = __shfl(comp, hsrc | (k >> 2), 64);
        float4 w4 = *(const float4*)(We1 + k * 128 + c0);
        ex0 += ak * w4.x; ex1 += ak * w4.y; ex2 += ak * w4.z; ex3 += ak * w4.w;
    }
    float inv = 1.f / (lden + 1e-16f);
    float o0 = (acc.x + ex0) * inv + ska.x;
    float o1 = (acc.y + ex1) * inv + ska.y;
    float o2 = (acc.z + ex2) * inv + skb.x;
    float o3 = (acc.w + ex3) * inv + skb.y;
    o0 = o0 > 0.f ? o0 : 0.01f * o0;
    o1 = o1 > 0.f ? o1 : 0.01f * o1;
    o2 = o2 > 0.f ? o2 : 0.01f * o2;
    o3 = o3 > 0.f ? o3 : 0.01f * o3;
    if (half == 0) {
        uint2 pk;
        pk.x = (unsigned)f2bf(o0) | ((unsigned)f2bf(o1) << 16);
        pk.y = (unsigned)f2bf(o2) | ((unsigned)f2bf(o3) << 16);
        *(uint2*)(h1 + (size_t)node * 128 + c0) = pk;
    }
}

// Layer 2: H=1, C=128. Half-wave (32-lane) dot per edge; lanes 0..7 of each
// half hold the chunk's scores.
__global__ __launch_bounds__(128, 4) void fused2_node(
    const unsigned short* __restrict__ P, const float* __restrict__ qWe,
    const float* __restrict__ ea, const float* __restrict__ We2,
    const int2* __restrict__ csr, const int* __restrict__ rowptr,
    float* __restrict__ out, int N)
{
    const int lane = threadIdx.x & 63;
    const int node = blockIdx.x * 2 + (threadIdx.x >> 6);
    if (node >= N) return;
    const int l32 = lane & 31, half = lane >> 5;
    const int c0 = l32 * 4;
    const int k16 = lane & 15;

    const int beg = rowptr[node];
    const int deg = rowptr[node + 1] - beg;

    uint2 su = *(const uint2*)(P + (size_t)node * 512 + 384 + c0);
    float2 ska = bf2(su.x), skb = bf2(su.y);
    float* outp = out + (size_t)node * 128 + c0;
    if (deg == 0) {
        if (half == 0) *(float4*)outp = make_float4(ska.x, ska.y, skb.x, skb.y);
        return;
    }

    uint2 qu = *(const uint2*)(P + (size_t)node * 512 + 256 + c0);
    float2 qa = bf2(qu.x), qb = bf2(qu.y);
    float qw = qWe[(size_t)node * 128 + k16];

    float4 acc = make_float4(0.f, 0.f, 0.f, 0.f);
    float accA = 0.f;
    float m = -INFINITY, lden = 0.f;

    int2 se = make_int2(0, 0);
    if (lane < deg) se = csr[beg + lane];

    for (int blk = 0; blk < deg; blk += 64) {
        if (blk) se = (blk + lane < deg) ? csr[beg + blk + lane] : make_int2(0, 0);
        const int bcnt = min(64, deg - blk);
        for (int cb = 0; cb < bcnt; cb += 16) {
            const int lim = min(16, bcnt - cb);
            uint4 kv[8]; float eav[8];
            // ---- gather phase ----
#pragma unroll
            for (int i = 0; i < 8; ++i) {
                if (2 * i < lim) {
                    int jj = cb + 2 * i + half;
                    int jc = min(jj, bcnt - 1);
                    int sb = __shfl(se.x, jc, 64);
                    int eb = __shfl(se.y, jc, 64);
                    kv[i]  = *(const uint4*)(P + (size_t)sb * 512 + l32 * 8);
                    eav[i] = ea[(size_t)eb * 16 + k16];
                }
            }
            // ---- score phase ----
            float my_s = -INFINITY;
#pragma unroll
            for (int i = 0; i < 8; ++i) {
                if (2 * i < lim) {
                    float2 ka = bf2(kv[i].x), kb = bf2(kv[i].z);
                    float p = qa.x * ka.x + qa.y * ka.y + qb.x * kb.x + qb.y * kb.y
                            + 0.5f * qw * eav[i];   // 2x dup within half
                    p += __shfl_xor(p, 1, 64);
                    p += __shfl_xor(p, 2, 64);
                    p += __shfl_xor(p, 4, 64);
                    p += __shfl_xor(p, 8, 64);
                    p += __shfl_xor(p, 16, 64);     // half-wide reduction
                    bool valid = (cb + 2 * i + half) < bcnt;
                    if (l32 == i) my_s = valid ? p * 0.08838834764831845f : -INFINITY;
                }
            }
            // ---- online softmax ----
            float cm = my_s;
#pragma unroll
            for (int mk = 1; mk < 64; mk <<= 1) cm = fmaxf(cm, __shfl_xor(cm, mk, 64));
            float m_new = fmaxf(m, cm);
            float scale = __expf(m - m_new);
            float ew = __expf(my_s - m_new);   // non-slot / invalid: 0
            float ds = ew;
#pragma unroll
            for (int mk = 1; mk < 64; mk <<= 1) ds += __shfl_xor(ds, mk, 64);
            lden = lden * scale + ds;
            acc.x *= scale; acc.y *= scale; acc.z *= scale; acc.w *= scale;
            accA *= scale;
            m = m_new;
            // ---- accumulate (my half's edges) ----
#pragma unroll
            for (int i = 0; i < 8; ++i) {
                if (2 * i < lim) {
                    float w = __shfl(ew, (lane & 32) | i, 64);
                    float2 va = bf2(kv[i].y), vb = bf2(kv[i].w);
                    acc.x += w * va.x; acc.y += w * va.y;
                    acc.z += w * vb.x; acc.w += w * vb.y;
                    accA += w * eav[i];
                }
            }
        }
    }
    // combine halves
    acc.x += __shfl_xor(acc.x, 32, 64); acc.y += __shfl_xor(acc.y, 32, 64);
    acc.z += __shfl_xor(acc.z, 32, 64); acc.w += __shfl_xor(acc.w, 32, 64);
    accA  += __shfl_xor(accA, 32, 64);

    float ex0 = 0.f, ex1 = 0.f, ex2 = 0.f, ex3 = 0.f;
#pragma unroll
    for (int k = 0; k < 16; ++k) {
        float ak = __shfl(accA, (lane & 48) | k, 64);
        float4 w4 = *(const float4*)(We2 + k * 128 + c0);
        ex0 += ak * w4.x; ex1 += ak * w4.y; ex2 += ak * w4.z; ex3 += ak * w4.w;
    }
    float inv = 1.f / (lden + 1e-16f);
    if (half == 0) {
        float4 o;
        o.x = (acc.x + ex0) * inv + ska.x;
        o.y = (acc.y + ex1) * inv + ska.y;
        o.z = (acc.z + ex2) * inv + skb.x;
        o.w = (acc.w + ex3) * inv + skb.y;
        *(float4*)outp = o;
    }
}

// ---------------- launch ----------------
extern "C" void kernel_launch(void* const* d_in, const int* in_sizes, int n_in,
                              void* d_out, int out_size, void* d_ws, size_t ws_size,
                              hipStream_t stream)
{
    const float* x  = (const float*)d_in[0];
    const int*   ei = (const int*)d_in[1];
    const float* ea = (const float*)d_in[2];
    const float *Wq1 = (const float*)d_in[3],  *bq1 = (const float*)d_in[4];
    const float *Wk1 = (const float*)d_in[5],  *bk1 = (const float*)d_in[6];
    const float *Wv1 = (const float*)d_in[7],  *bv1 = (const float*)d_in[8];
    const float *We1 = (const float*)d_in[9],  *be1 = (const float*)d_in[10];
    const float *Ws1 = (const float*)d_in[11], *bs1 = (const float*)d_in[12];
    const float *Wq2 = (const float*)d_in[13], *bq2 = (const float*)d_in[14];
    const float *Wk2 = (const float*)d_in[15], *bk2 = (const float*)d_in[16];
    const float *Wv2 = (const float*)d_in[17], *bv2 = (const float*)d_in[18];
    const float *We2 = (const float*)d_in[19], *be2 = (const float*)d_in[20];
    const float *Ws2 = (const float*)d_in[21], *bs2 = (const float*)d_in[22];

    const int N = in_sizes[0] / 128;
    const int E = in_sizes[1] / 2;

    char* ws = (char*)d_ws;
    size_t off = 0;
    auto alloc = [&](size_t bytes) -> void* {
        void* p = ws + off;
        off = (off + bytes + 255) & ~(size_t)255;
        return p;
    };
    unsigned short* xb  = (unsigned short*)alloc((size_t)N * 128 * 2);
    unsigned short* P   = (unsigned short*)alloc((size_t)N * 512 * 2);  // bf16 [kv-interleave | q | s]
    unsigned short* h1b = (unsigned short*)alloc((size_t)N * 128 * 2);
    unsigned short* Wt1 = (unsigned short*)alloc((size_t)640 * 128 * 2);
    unsigned short* Wt2 = (unsigned short*)alloc((size_t)640 * 128 * 2);
    float* bias1 = (float*)alloc(640 * 4);
    float* bias2 = (float*)alloc(640 * 4);
    float* qWe   = (float*)alloc((size_t)N * 128 * 4);
    int*  deg    = (int*)alloc((size_t)N * 4);
    int*  rowptr = (int*)alloc((size_t)(N + 1) * 4);
    int*  cursor = (int*)alloc((size_t)N * 4);
    int2* csr    = (int2*)alloc((size_t)E * 8);

    dim3 gemm_grid1((N + 63) / 64, 10);
    dim3 gemm_grid2((N + 63) / 64, 9);   // layer-2 qWe needs only cols [512,528)
    const int tn = N * 128;
    const int node_blocks = (N + 1) / 2;
    const int prep_blocks = (640 * 128 + 255) / 256;

    // ---- prep (independent of everything else) ----
    convert_x<<<(tn + 255) / 256, 256, 0, stream>>>(x, xb, tn);
    prep_w<<<prep_blocks, 256, 0, stream>>>(Wq1, bq1, Wk1, bk1, Wv1, bv1, be1, Ws1, bs1, We1, 8, Wt1, bias1);
    prep_w<<<prep_blocks, 256, 0, stream>>>(Wq2, bq2, Wk2, bk2, Wv2, bv2, be2, Ws2, bs2, We2, 1, Wt2, bias2);

    // ---- CSR build (shared by both layers) ----
    hipMemsetAsync(deg, 0, (size_t)N * 4, stream);
    degree_kernel<<<(E + 255) / 256, 256, 0, stream>>>(ei, deg, E);
    scan_kernel<<<1, 1024, 0, stream>>>(deg, rowptr, cursor, N);
    scatter_kernel<<<(E + 255) / 256, 256, 0, stream>>>(ei, cursor, csr, E);

    // ---- layer 1 (H=8, C=16, concat) ----
    gemm_bf16<<<gemm_grid1, 256, 0, stream>>>(xb, N, Wt1, bias1, P, qWe);
    fused1_node<<<node_blocks, 128, 0, stream>>>(P, qWe, ea, We1, csr, rowptr, h1b, N);

    // ---- layer 2 (H=1, C=128, mean==identity) ----
    gemm_bf16<<<gemm_grid2, 256, 0, stream>>>(h1b, N, Wt2, bias2, P, qWe);
    fused2_node<<<node_blocks, 128, 0, stream>>>(P, qWe, ea, We2, csr, rowptr, (float*)d_out, N);
}